// Round 4
// baseline (747.989 us; speedup 1.0000x reference)
//
#include <hip/hip_runtime.h>

// ===== Problem constants =====
constexpr int L_TXT = 256, L_IMG = 2048, SEQ = 2304;
constexpr int DM = 2048, NH = 16, DH = 128;
constexpr int NSPLIT = 4;      // flash split-K factor
constexpr int SSTR = 32;       // slot stride in unsigneds (128 B) - avoids atomic cacheline ping-pong

typedef __attribute__((ext_vector_type(8))) __bf16 bf16x8;
typedef __attribute__((ext_vector_type(4))) float f32x4;

// Runtime dtype flag: 0 = fp32 storage, 1 = bf16 (detected from rope_cos[0]).
__device__ __forceinline__ float ldin(const void* p, size_t i, int bf) {
  return bf ? (float)((const __bf16*)p)[i] : ((const float*)p)[i];
}
__device__ __forceinline__ float slot_scale(const unsigned* s) {
  return fmaxf(__uint_as_float(*s) / 127.0f, 1e-8f);
}
__device__ __forceinline__ float qclamp(float x, float sc) {
  float q = rintf(x / sc);     // RNE, matches jnp.round
  return fminf(fmaxf(q, -127.0f), 127.0f);
}
__device__ __forceinline__ float block_allmax_n(float v) {  // any blockDim multiple of 64 (<=1024)
  #pragma unroll
  for (int off = 32; off; off >>= 1) v = fmaxf(v, __shfl_xor(v, off));
  __shared__ float sm[16];
  int nw = blockDim.x >> 6;
  __syncthreads();
  if ((threadIdx.x & 63) == 0) sm[threadIdx.x >> 6] = v;
  __syncthreads();
  float m = sm[0];
  for (int i = 1; i < nw; i++) m = fmaxf(m, sm[i]);
  return m;
}

__global__ void detect_k(const void* cosp, int* flag) {
  if (threadIdx.x == 0) *flag = (((const unsigned short*)cosp)[0] != 0) ? 1 : 0;
}

struct Ptrs8 { const void* p[8]; };

// ===== Weight quantization (vectorized): scales + int-grid bf16 weights =====
__global__ void quant_weights_k(Ptrs8 win, __bf16* __restrict__ wq, float* __restrict__ scales,
                                const int* __restrict__ flagp) {
  const int bf = *flagp;
  int row = blockIdx.x, mat = blockIdx.y, t = threadIdx.x;
  float v[8];
  if (bf) {
    union { int4 q; __bf16 h[8]; } u;
    u.q = ((const int4*)((const __bf16*)win.p[mat] + (size_t)row * DM))[t];
    #pragma unroll
    for (int j = 0; j < 8; j++) v[j] = (float)u.h[j];
  } else {
    const float4* p = (const float4*)((const float*)win.p[mat] + (size_t)row * DM);
    float4 a = p[t * 2], b = p[t * 2 + 1];
    v[0]=a.x; v[1]=a.y; v[2]=a.z; v[3]=a.w; v[4]=b.x; v[5]=b.y; v[6]=b.z; v[7]=b.w;
  }
  float m = 0.f;
  #pragma unroll
  for (int j = 0; j < 8; j++) m = fmaxf(m, fabsf(v[j]));
  m = block_allmax_n(m);
  float sc = fmaxf(m / 127.0f, 1e-8f);
  if (t == 0) scales[mat * DM + row] = sc;
  union { int4 q; __bf16 h[8]; } o;
  #pragma unroll
  for (int j = 0; j < 8; j++) o.h[j] = (__bf16)qclamp(v[j], sc);
  ((int4*)(wq + (size_t)mat * DM * DM + (size_t)row * DM))[t] = o.q;
}
// fallback: scales only
__global__ void weight_scales_k(Ptrs8 win, float* __restrict__ scales, const int* __restrict__ flagp) {
  const int bf = *flagp;
  int row = blockIdx.x, mat = blockIdx.y, t = threadIdx.x;
  float m = 0.f;
  for (int c = t; c < DM; c += 256) m = fmaxf(m, fabsf(ldin(win.p[mat], (size_t)row * DM + c, bf)));
  m = block_allmax_n(m);
  if (t == 0) scales[mat * DM + row] = fmaxf(m / 127.0f, 1e-8f);
}

// ===== absmax of hidden + encoder in one pass (vectorized x8) =====
__global__ void absmax_he_k(const void* __restrict__ hs, const void* __restrict__ es,
                            unsigned* s0, unsigned* s1, const int* __restrict__ flagp) {
  const int bf = *flagp;
  const int n18 = L_IMG * DM / 8, n28 = L_TXT * DM / 8;
  float m1 = 0.f, m2 = 0.f;
  for (int i = blockIdx.x * 256 + threadIdx.x; i < n18 + n28; i += gridDim.x * 256) {
    bool h = i < n18;
    const void* src = h ? hs : es;
    int j = h ? i : i - n18;
    float lm = 0.f;
    if (bf) {
      union { int4 q; __bf16 x[8]; } u; u.q = ((const int4*)src)[j];
      #pragma unroll
      for (int k = 0; k < 8; k++) lm = fmaxf(lm, fabsf((float)u.x[k]));
    } else {
      const float4* p = (const float4*)src;
      float4 a = p[j * 2], b = p[j * 2 + 1];
      lm = fmaxf(fmaxf(fmaxf(fabsf(a.x), fabsf(a.y)), fmaxf(fabsf(a.z), fabsf(a.w))),
                 fmaxf(fmaxf(fabsf(b.x), fabsf(b.y)), fmaxf(fabsf(b.z), fabsf(b.w))));
    }
    if (h) m1 = fmaxf(m1, lm); else m2 = fmaxf(m2, lm);
  }
  m1 = block_allmax_n(m1);
  __syncthreads();
  m2 = block_allmax_n(m2);
  if (threadIdx.x == 0) { atomicMax(s0, __float_as_uint(m1)); atomicMax(s1, __float_as_uint(m2)); }
}

// ===== quantize hidden+encoder to int-grid bf16 (vectorized x8) =====
__global__ void quant_he_k(const void* __restrict__ hs, const void* __restrict__ es,
                           const unsigned* __restrict__ slots, __bf16* __restrict__ hqo,
                           __bf16* __restrict__ eqo, const int* __restrict__ flagp) {
  const int bf = *flagp;
  const int n18 = L_IMG * DM / 8, n28 = L_TXT * DM / 8;
  float sc0 = slot_scale(slots), sc1 = slot_scale(slots + SSTR);
  for (int i = blockIdx.x * 256 + threadIdx.x; i < n18 + n28; i += gridDim.x * 256) {
    bool h = i < n18;
    const void* src = h ? hs : es;
    int j = h ? i : i - n18;
    float sc = h ? sc0 : sc1;
    float v[8];
    if (bf) {
      union { int4 q; __bf16 x[8]; } u; u.q = ((const int4*)src)[j];
      #pragma unroll
      for (int k = 0; k < 8; k++) v[k] = (float)u.x[k];
    } else {
      const float4* p = (const float4*)src;
      float4 a = p[j * 2], b = p[j * 2 + 1];
      v[0]=a.x; v[1]=a.y; v[2]=a.z; v[3]=a.w; v[4]=b.x; v[5]=b.y; v[6]=b.z; v[7]=b.w;
    }
    union { int4 q; __bf16 x[8]; } o;
    #pragma unroll
    for (int k = 0; k < 8; k++) o.x[k] = (__bf16)qclamp(v[k], sc);
    ((int4*)(h ? hqo : eqo))[j] = o.q;
  }
}

// ===== quantize fp32 attn-out to int-grid bf16 (vectorized x8) =====
__global__ void quant_f32x8_k(const float* __restrict__ x, int n8,
                              const unsigned* __restrict__ slot, __bf16* __restrict__ out) {
  float sc = slot_scale(slot);
  for (int i = blockIdx.x * 256 + threadIdx.x; i < n8; i += gridDim.x * 256) {
    float4 a = ((const float4*)x)[i * 2], b = ((const float4*)x)[i * 2 + 1];
    union { int4 q; __bf16 h[8]; } o;
    o.h[0]=(__bf16)qclamp(a.x,sc); o.h[1]=(__bf16)qclamp(a.y,sc);
    o.h[2]=(__bf16)qclamp(a.z,sc); o.h[3]=(__bf16)qclamp(a.w,sc);
    o.h[4]=(__bf16)qclamp(b.x,sc); o.h[5]=(__bf16)qclamp(b.y,sc);
    o.h[6]=(__bf16)qclamp(b.z,sc); o.h[7]=(__bf16)qclamp(b.w,sc);
    ((int4*)out)[i] = o.q;
  }
}
// fallback absmax (non-split flash path)
__global__ void absmax_f32_k(const float* __restrict__ x, int n, unsigned* slot) {
  float m = 0.f;
  for (int i = blockIdx.x * 256 + threadIdx.x; i < n; i += gridDim.x * 256)
    m = fmaxf(m, fabsf(x[i]));
  m = block_allmax_n(m);
  if (threadIdx.x == 0) atomicMax(slot, __float_as_uint(m));
}

// ===== fused: rmsnorm(q)+absmax, rmsnorm(k)+absmax, absmax(v) =====
__global__ void rms_absmax_v_k(float* __restrict__ qf, float* __restrict__ kf, float* __restrict__ vf,
                               const void* nq, const void* naq, const void* nk, const void* nak,
                               unsigned* __restrict__ slots, const int* __restrict__ flagp) {
  const int bf = *flagp;
  const int t = threadIdx.x, lane = t & 63, wave = t >> 6;   // 1024 thr = 16 waves
  float wqt0 = ldin(naq, lane, bf), wqt1 = ldin(naq, lane + 64, bf);
  float wqi0 = ldin(nq,  lane, bf), wqi1 = ldin(nq,  lane + 64, bf);
  float wkt0 = ldin(nak, lane, bf), wkt1 = ldin(nak, lane + 64, bf);
  float wki0 = ldin(nk,  lane, bf), wki1 = ldin(nk,  lane + 64, bf);
  const int NR = NH * SEQ;
  float mx[6] = {0.f, 0.f, 0.f, 0.f, 0.f, 0.f};
  for (int row = blockIdx.x * 16 + wave; row < 3 * NR; row += gridDim.x * 16) {
    int tns = row / NR, r2 = row - tns * NR;
    int s = r2 % SEQ; bool txt = s < L_TXT;
    float* p = (tns == 0 ? qf : tns == 1 ? kf : vf) + (size_t)r2 * DH;
    float v0 = p[lane], v1 = p[lane + 64];
    if (tns < 2) {
      float ss = v0 * v0 + v1 * v1;
      #pragma unroll
      for (int off = 32; off; off >>= 1) ss += __shfl_xor(ss, off);
      float r = rsqrtf(ss * (1.0f / 128.0f) + 1e-6f);
      float w0, w1;
      if (tns == 0) { w0 = txt ? wqt0 : wqi0; w1 = txt ? wqt1 : wqi1; }
      else          { w0 = txt ? wkt0 : wki0; w1 = txt ? wkt1 : wki1; }
      v0 *= r * w0; v1 *= r * w1;
      p[lane] = v0; p[lane + 64] = v1;
    }
    int idx = tns * 2 + (txt ? 0 : 1);
    mx[idx] = fmaxf(mx[idx], fmaxf(fabsf(v0), fabsf(v1)));
  }
  #pragma unroll
  for (int off = 32; off; off >>= 1)
    #pragma unroll
    for (int j = 0; j < 6; j++) mx[j] = fmaxf(mx[j], __shfl_xor(mx[j], off));
  __shared__ float smx[16][6];
  if (lane == 0)
    #pragma unroll
    for (int j = 0; j < 6; j++) smx[wave][j] = mx[j];
  __syncthreads();
  if (t == 0) {
    #pragma unroll
    for (int j = 0; j < 6; j++) {
      float m = smx[0][j];
      for (int i = 1; i < 16; i++) m = fmaxf(m, smx[i][j]);
      atomicMax(slots + (2 + j) * SSTR, __float_as_uint(m));
    }
  }
}

// ===== fused rope for q and k: quantize (dequant) + rotate + bf16 =====
__global__ void rope2_k(const float* __restrict__ qf, const float* __restrict__ kf,
                        const void* cosb, const void* sinb, const unsigned* __restrict__ slots,
                        __bf16* __restrict__ qb, __bf16* __restrict__ kb, const int* __restrict__ flagp) {
  const int bf = *flagp;
  const int NP = NH * SEQ * 64;
  for (int i = blockIdx.x * 256 + threadIdx.x; i < 2 * NP; i += gridDim.x * 256) {
    int tns = i >= NP;
    int j = i - tns * NP;
    int pr = j & 63, rowg = j >> 6;
    int s = rowg % SEQ;
    const float* src = tns ? kf : qf;
    __bf16* dst = tns ? kb : qb;
    float sc = slot_scale(slots + (tns ? 4 : 2) * SSTR + (s < L_TXT ? 0 : SSTR));
    size_t base = (size_t)rowg * DH + pr * 2;
    float2 x2 = *(const float2*)(src + base);
    float q0 = qclamp(x2.x, sc) * sc, q1 = qclamp(x2.y, sc) * sc;
    float c0 = ldin(cosb, s * DH + 2 * pr, bf), c1 = ldin(cosb, s * DH + 2 * pr + 1, bf);
    float s0 = ldin(sinb, s * DH + 2 * pr, bf), s1 = ldin(sinb, s * DH + 2 * pr + 1, bf);
    dst[base]     = (__bf16)(q0 * c0 - q1 * s0);
    dst[base + 1] = (__bf16)(q1 * c1 + q0 * s1);
  }
}

// ===== V: quantize + transpose [NH][SEQ][DH] -> [NH][DH][SEQ] =====
__global__ void quant_transpose_v_k(const float* __restrict__ v, const unsigned* __restrict__ slots,
                                    __bf16* __restrict__ vt) {
  __shared__ float tile[64][65];
  int t = threadIdx.x;
  int s0 = blockIdx.x * 64, d0 = blockIdx.y * 64, h = blockIdx.z;
  #pragma unroll
  for (int i = 0; i < 16; i++) {
    int r = i * 4 + (t >> 6), c = t & 63;
    tile[r][c] = v[((size_t)(h * SEQ) + s0 + r) * DH + d0 + c];
  }
  __syncthreads();
  float sc = slot_scale(slots + (s0 < L_TXT ? 6 : 7) * SSTR);
  #pragma unroll
  for (int i = 0; i < 16; i++) {
    int d = i * 4 + (t >> 6), s = t & 63;
    float q = qclamp(tile[s][d], sc) * sc;
    vt[((size_t)(h * DH) + d0 + d) * SEQ + s0 + s] = (__bf16)q;
  }
}

// ===== GEMM (fused launches) =====
struct GemmArgs {
  const __bf16 *hq, *eq, *attnq;
  const __bf16* wqp;
  const void* Wraw[8];
  const float* wsc;
  const void* bias[8];
  float* outs[3];
  void* dout;
  const unsigned* slots;
  const int* flagp;
};
template<int MODE, int QW>
__global__ __launch_bounds__(256, 2)
void gemm_f(GemmArgs a) {
  const int bf = *a.flagp;
  constexpr int K = DM;
  __shared__ __bf16 As[128][72];
  __shared__ __bf16 Ws[128][72];
  const int t = threadIdx.x, lane = t & 63, wave = t >> 6;
  const int l15 = lane & 15, quad = lane >> 4;
  const int n0 = blockIdx.x * 128, y = blockIdx.y;
  int mat, outrow; const __bf16* A; const unsigned* aslot;
  if (MODE == 0) {
    bool txt = y < 2;
    mat = blockIdx.z + (txt ? 3 : 0);
    A = (txt ? a.eq : a.hq) + (size_t)(txt ? y * 128 : (y - 2) * 128) * K;
    outrow = y * 128;
    aslot = a.slots + (txt ? SSTR : 0);
  } else {
    bool img = y < 16;
    mat = img ? 6 : 7;
    A = a.attnq + (size_t)(img ? L_TXT + y * 128 : (y - 16) * 128) * K;
    outrow = img ? y * 128 : L_IMG + (y - 16) * 128;
    aslot = a.slots + 8 * SSTR;
  }
  const __bf16* Wq = QW ? a.wqp + (size_t)mat * DM * DM : nullptr;
  const void* Wr = a.Wraw[mat];
  const float* wrow = a.wsc + mat * DM;
  int wm = (wave & 1) * 64, wn = (wave >> 1) * 64;
  f32x4 acc[4][4] = {};
  int sr = t >> 3, sc = (t & 7) * 8;
  float wsc4[4];
  if (!QW) {
    #pragma unroll
    for (int p = 0; p < 4; p++) wsc4[p] = wrow[n0 + p * 32 + sr];
  }
  for (int k0 = 0; k0 < K; k0 += 64) {
    __syncthreads();
    #pragma unroll
    for (int p = 0; p < 4; p++) {
      int r = p * 32 + sr;
      *(int4*)&As[r][sc] = *(const int4*)&A[(size_t)r * K + k0 + sc];
      if (QW) {
        *(int4*)&Ws[r][sc] = *(const int4*)&Wq[(size_t)(n0 + r) * K + k0 + sc];
      } else {
        union { bf16x8 v; __bf16 h[8]; } q;
        if (bf) {
          union { int4 v; __bf16 h[8]; } u;
          u.v = *(const int4*)((const __bf16*)Wr + (size_t)(n0 + r) * K + k0 + sc);
          #pragma unroll
          for (int j = 0; j < 8; j++) q.h[j] = (__bf16)qclamp((float)u.h[j], wsc4[p]);
        } else {
          const float* wp = (const float*)Wr + (size_t)(n0 + r) * K + k0 + sc;
          float4 x = *(const float4*)wp, z = *(const float4*)(wp + 4);
          q.h[0]=(__bf16)qclamp(x.x,wsc4[p]); q.h[1]=(__bf16)qclamp(x.y,wsc4[p]);
          q.h[2]=(__bf16)qclamp(x.z,wsc4[p]); q.h[3]=(__bf16)qclamp(x.w,wsc4[p]);
          q.h[4]=(__bf16)qclamp(z.x,wsc4[p]); q.h[5]=(__bf16)qclamp(z.y,wsc4[p]);
          q.h[6]=(__bf16)qclamp(z.z,wsc4[p]); q.h[7]=(__bf16)qclamp(z.w,wsc4[p]);
        }
        *(bf16x8*)&Ws[r][sc] = q.v;
      }
    }
    __syncthreads();
    #pragma unroll
    for (int kk = 0; kk < 64; kk += 32) {
      bf16x8 af[4], bfr[4];
      #pragma unroll
      for (int i = 0; i < 4; i++) {
        af[i]  = *(const bf16x8*)&As[wm + i * 16 + l15][kk + quad * 8];
        bfr[i] = *(const bf16x8*)&Ws[wn + i * 16 + l15][kk + quad * 8];
      }
      #pragma unroll
      for (int i = 0; i < 4; i++)
        #pragma unroll
        for (int j = 0; j < 4; j++)
          acc[i][j] = __builtin_amdgcn_mfma_f32_16x16x32_bf16(af[i], bfr[j], acc[i][j], 0, 0, 0);
    }
  }
  float asc = slot_scale(aslot);
  #pragma unroll
  for (int j = 0; j < 4; j++) {
    int gn = n0 + wn + j * 16 + l15;
    float wsb = wrow[gn] * asc;
    float bv = ldin(a.bias[mat], gn, bf);
    #pragma unroll
    for (int i = 0; i < 4; i++)
      #pragma unroll
      for (int r = 0; r < 4; r++) {
        int gm = wm + i * 16 + quad * 4 + r;    // C/D: col=lane&15, row=quad*4+reg (m89)
        float val = acc[i][j][r] * wsb + bv;
        if (MODE == 0) {
          a.outs[blockIdx.z][(size_t)(gn >> 7) * (SEQ * DH) + (size_t)(outrow + gm) * DH + (gn & 127)] = val;
        } else {
          size_t idx = (size_t)(outrow + gm) * DM + gn;
          if (bf) ((__bf16*)a.dout)[idx] = (__bf16)val; else ((float*)a.dout)[idx] = val;
        }
      }
  }
}

// ===== Flash attention: Br=64 (4 waves x 16 rows), Bc=32, online softmax =====
// Round-9. Round-8 post-mortem: (256,3)'s 168-reg budget STILL spilled (WRITE
// 707 MB ~= round-7's 716; arch VGPR 72 + AGPRs + 32 prefetch regs + transients
// exceed it). Fighting the allocator at +-10 regs lost two rounds; this round
// gives it decisive headroom instead: Bc 64->32 halves the staged bytes/tile,
// so prefetch regs drop 32->16 and accS 16->8. Enumeration: qf 16 + prefetch 16
// + accS 8 + accO 32 + m/l 8 + temps/addr ~20 ~= 100 regs, ~70 under budget --
// spill impossible rather than unlikely. LDS 25088 B (Ks 32x304 + Vs 128x80 +
// Ps 64x80): occupancy purely reg-limited, ~4 waves/SIMD reachable at ~100 regs.
// Cost: 2x tiles (72) -> 2x barriers + 2x accO-rescale VALU (~5-10% tax), paid
// for by killing 630 MB of scratch traffic. Round-1 machinery retained:
// reg prefetch of next tile, lgkm-only raw barriers (no vmcnt(0) drain),
// setprio around MFMA, separate Ps (2 barriers/tile), fused softmax.
template<int SPLIT>
__global__ __launch_bounds__(256, 3)
void flash_attn_k(const __bf16* __restrict__ Qb, const __bf16* __restrict__ Kb,
                  const __bf16* __restrict__ Vt, float* __restrict__ O,
                  float* __restrict__ Op, float* __restrict__ Mp, float* __restrict__ Lp) {
  __shared__ __align__(16) char smem[9728 + 10240 + 5120];
  auto Ks = (__bf16(*)[152])smem;                  // 32 K-rows, stride 304 B
  auto Vs = (__bf16(*)[40])(smem + 9728);          // 128 d-rows, stride 80 B
  auto Ps = (__bf16(*)[40])(smem + 9728 + 10240);  // 64 q-rows, stride 80 B
  const int t = threadIdx.x, lane = t & 63, wave = t >> 6;
  const int l15 = lane & 15, quad = lane >> 4;
  const int h = blockIdx.y, s0 = blockIdx.x * 64, qr = wave * 16;
  const float fscale = 0.08838834764831845f * 1.4426950408889634f;  // sm_scale*log2e

  bf16x8 qf[4];
  #pragma unroll
  for (int kk = 0; kk < 4; kk++)
    qf[kk] = *(const bf16x8*)&Qb[(size_t)(h * SEQ + s0 + qr + l15) * DH + kk * 32 + quad * 8];

  f32x4 accO[8] = {};
  float m_st[4], l_st[4];
  #pragma unroll
  for (int r = 0; r < 4; r++) { m_st[r] = -1e30f; l_st[r] = 0.f; }

  const int NT = SEQ / 32;                       // 72 tiles
  const int ktb = SPLIT ? blockIdx.z * (NT / NSPLIT) : 0;
  const int kte = SPLIT ? ktb + (NT / NSPLIT) : NT;

  const int krr = t >> 4, krc = (t & 15) * 8;    // K staging: 2 x 16 rows, 128 cols
  const int vrr = t >> 2, vrc = (t & 3) * 8;     // V staging: 2 x 64 d-rows, 32 cols
  int4 kreg[2], vreg[2];
  #pragma unroll
  for (int p = 0; p < 2; p++) {
    kreg[p] = *(const int4*)&Kb[(size_t)(h * SEQ + ktb * 32 + p * 16 + krr) * DH + krc];
    vreg[p] = *(const int4*)&Vt[(size_t)(h * DH + p * 64 + vrr) * SEQ + ktb * 32 + vrc];
  }

  for (int kt = ktb; kt < kte; kt++) {
    // B1: all waves done reading Ks (QK of tile kt-1) and Vs (PV of kt-1).
    // lgkm-only drain: prefetch global loads stay in flight across the barrier.
    asm volatile("s_waitcnt lgkmcnt(0)" ::: "memory");
    __builtin_amdgcn_s_barrier();
    #pragma unroll
    for (int p = 0; p < 2; p++) {
      *(int4*)&Ks[p * 16 + krr][krc] = kreg[p];
      *(int4*)&Vs[p * 64 + vrr][vrc] = vreg[p];
    }
    if (kt + 1 < kte) {   // next tile's loads complete under this tile's compute
      #pragma unroll
      for (int p = 0; p < 2; p++) {
        kreg[p] = *(const int4*)&Kb[(size_t)(h * SEQ + (kt + 1) * 32 + p * 16 + krr) * DH + krc];
        vreg[p] = *(const int4*)&Vt[(size_t)(h * DH + p * 64 + vrr) * SEQ + (kt + 1) * 32 + vrc];
      }
    }
    // B2: staging visible.
    asm volatile("s_waitcnt lgkmcnt(0)" ::: "memory");
    __builtin_amdgcn_s_barrier();

    f32x4 accS[2] = {};
    __builtin_amdgcn_s_setprio(1);
    #pragma unroll
    for (int kk = 0; kk < 4; kk++)
      #pragma unroll
      for (int ni = 0; ni < 2; ni++) {
        bf16x8 bk = *(const bf16x8*)&Ks[ni * 16 + l15][kk * 32 + quad * 8];
        accS[ni] = __builtin_amdgcn_mfma_f32_16x16x32_bf16(qf[kk], bk, accS[ni], 0, 0, 0);
      }
    __builtin_amdgcn_s_setprio(0);

    // Fused softmax per output row r: rowmax -> alpha -> exp/sum -> rescale accO.
    #pragma unroll
    for (int r = 0; r < 4; r++) {
      float rm = fmaxf(accS[0][r], accS[1][r]);
      #pragma unroll
      for (int off = 8; off > 0; off >>= 1) rm = fmaxf(rm, __shfl_xor(rm, off));
      float mn = fmaxf(m_st[r], rm);
      float al = exp2f((m_st[r] - mn) * fscale);
      m_st[r] = mn;
      float rs = 0.f;
      #pragma unroll
      for (int ni = 0; ni < 2; ni++) {
        float pv = exp2f((accS[ni][r] - mn) * fscale);
        accS[ni][r] = pv;
        rs += pv;
      }
      #pragma unroll
      for (int off = 8; off > 0; off >>= 1) rs += __shfl_xor(rs, off);
      l_st[r] = l_st[r] * al + rs;
      #pragma unroll
      for (int di = 0; di < 8; di++)
        accO[di][r] *= al;
    }
    // Ps rows [qr, qr+16) are wave-private (separate buffer -- no barrier).
    #pragma unroll
    for (int ni = 0; ni < 2; ni++)
      #pragma unroll
      for (int r = 0; r < 4; r++)
        Ps[qr + quad * 4 + r][ni * 16 + l15] = (__bf16)accS[ni][r];
    // PV (K=32, single k-step): Ps same-wave RAW via compiler lgkmcnt; Vs stable since B2.
    __builtin_amdgcn_s_setprio(1);
    {
      bf16x8 pa = *(const bf16x8*)&Ps[qr + l15][quad * 8];
      #pragma unroll
      for (int di = 0; di < 8; di++) {
        bf16x8 vb = *(const bf16x8*)&Vs[di * 16 + l15][quad * 8];
        accO[di] = __builtin_amdgcn_mfma_f32_16x16x32_bf16(pa, vb, accO[di], 0, 0, 0);
      }
    }
    __builtin_amdgcn_s_setprio(0);
  }
  if (SPLIT) {
    const size_t SP = (size_t)NH * SEQ * DH;
    const int sp = blockIdx.z;
    #pragma unroll
    for (int r = 0; r < 4; r++) {
      int gs = s0 + qr + quad * 4 + r;
      size_t ib = sp * SP + ((size_t)h * SEQ + gs) * DH;
      if (l15 == 0) {
        Mp[(size_t)sp * NH * SEQ + h * SEQ + gs] = m_st[r];
        Lp[(size_t)sp * NH * SEQ + h * SEQ + gs] = l_st[r];
      }
      #pragma unroll
      for (int di = 0; di < 8; di++)
        Op[ib + di * 16 + l15] = accO[di][r];
    }
  } else {
    #pragma unroll
    for (int r = 0; r < 4; r++) {
      float inv = 1.0f / l_st[r];
      int gs = s0 + qr + quad * 4 + r;
      #pragma unroll
      for (int di = 0; di < 8; di++)
        O[(size_t)gs * DM + h * DH + di * 16 + l15] = accO[di][r] * inv;
    }
  }
}

// Merge NSPLIT partials + global absmax of result (feeds attn-out quant).
__global__ void flash_combine_k(const float* __restrict__ Op, const float* __restrict__ Mp,
                                const float* __restrict__ Lp, float* __restrict__ O,
                                unsigned* __restrict__ slot8) {
  const float fscale = 0.08838834764831845f * 1.4426950408889634f;
  const int t = threadIdx.x, lane = t & 63, w = t >> 6;   // 1024 thr, 16 waves
  const size_t SP = (size_t)NH * SEQ * DH, MR = (size_t)NH * SEQ;
  float lm = 0.f;
  for (int row = blockIdx.x * 16 + w; row < NH * SEQ; row += gridDim.x * 16) {
    float m0 = Mp[row], m1 = Mp[MR + row], m2 = Mp[2 * MR + row], m3 = Mp[3 * MR + row];
    float M = fmaxf(fmaxf(m0, m1), fmaxf(m2, m3));
    float w0 = exp2f((m0 - M) * fscale), w1 = exp2f((m1 - M) * fscale);
    float w2 = exp2f((m2 - M) * fscale), w3 = exp2f((m3 - M) * fscale);
    float inv = 1.0f / (Lp[row] * w0 + Lp[MR + row] * w1 + Lp[2 * MR + row] * w2 + Lp[3 * MR + row] * w3);
    int h = row / SEQ, s = row % SEQ;
    size_t ob = (size_t)s * DM + h * DH, ib = (size_t)row * DH;
    #pragma unroll
    for (int j = 0; j < 2; j++) {
      int d = lane + j * 64;
      float v = (Op[ib + d] * w0 + Op[SP + ib + d] * w1 +
                 Op[2 * SP + ib + d] * w2 + Op[3 * SP + ib + d] * w3) * inv;
      O[ob + d] = v;
      lm = fmaxf(lm, fabsf(v));
    }
  }
  lm = block_allmax_n(lm);
  if (t == 0) atomicMax(slot8, __float_as_uint(lm));
}

extern "C" void kernel_launch(void* const* d_in, const int* in_sizes, int n_in,
                              void* d_out, int out_size, void* d_ws, size_t ws_size,
                              hipStream_t stream) {
  (void)in_sizes; (void)n_in; (void)out_size;
  const void* hs   = d_in[0];
  const void* es   = d_in[1];
  const void* cosb = d_in[2];
  const void* sinb = d_in[3];
  const void* W[8]; const void* Bv[8];
  for (int i = 0; i < 8; i++) { W[i] = d_in[4 + 2 * i]; Bv[i] = d_in[5 + 2 * i]; }
  const void* nq  = d_in[20];
  const void* nk  = d_in[21];
  const void* naq = d_in[22];
  const void* nak = d_in[23];

  char* ws = (char*)d_ws;
  size_t off = 0;
  auto take = [&](size_t b) { char* p = ws + off; off += (b + 255) & ~(size_t)255; return p; };
  const size_t T = (size_t)NH * SEQ * DH * 4;      // 18.87 MB (one fp32 qkv tensor)

  unsigned* slots = (unsigned*)take(16 * SSTR * 4);   // 9 scale slots + flag, 128 B apart
  int* flagp = (int*)(slots + 15 * SSTR);
  float* wsc = (float*)take(8ull * DM * 4);

  size_t here = off;
  size_t need_base  = 4 * T + T + 3 * (T / 2) + 2 * ((size_t)NSPLIT * NH * SEQ * 4 + 256) + 1024;
  bool do_split = here + need_base <= ws_size;
  size_t region_sz = do_split ? 4 * T : 3 * T;

  char* region = take(region_sz);                  // qf,kf,vf; later Opart(+attnq)
  float* qf = (float*)region;
  float* kf = (float*)(region + T);
  float* vf = (float*)(region + 2 * T);
  float* Opart = (float*)region;
  __bf16* attnq = (__bf16*)region;                 // after combine (Opart dead)
  char* attnfR = take(T);                          // hq+eq early; attnf after flash
  __bf16* hq = (__bf16*)attnfR;
  __bf16* eq = (__bf16*)(attnfR + (size_t)L_IMG * DM * 2);
  float* attnf = (float*)attnfR;
  __bf16* qb  = (__bf16*)take(T / 2);
  __bf16* kb  = (__bf16*)take(T / 2);
  __bf16* vtb = (__bf16*)take(T / 2);
  float* Mpart = (float*)take((size_t)NSPLIT * NH * SEQ * 4);
  float* Lpart = (float*)take((size_t)NSPLIT * NH * SEQ * 4);
  bool do_prequant = (off + 8ull * DM * DM * 2 + 256 <= ws_size);
  __bf16* wq = do_prequant ? (__bf16*)take(8ull * DM * DM * 2) : nullptr;

  hipMemsetAsync(slots, 0, 16 * SSTR * 4, stream);
  detect_k<<<1, 64, 0, stream>>>(cosb, flagp);

  Ptrs8 win;
  for (int i = 0; i < 8; i++) win.p[i] = W[i];
  if (do_prequant)
    quant_weights_k<<<dim3(DM, 8), 256, 0, stream>>>(win, wq, wsc, flagp);
  else
    weight_scales_k<<<dim3(DM, 8), 256, 0, stream>>>(win, wsc, flagp);

  absmax_he_k<<<512, 256, 0, stream>>>(hs, es, slots, slots + SSTR, flagp);
  quant_he_k<<<1024, 256, 0, stream>>>(hs, es, slots, hq, eq, flagp);

  GemmArgs ga;
  ga.hq = hq; ga.eq = eq; ga.attnq = attnq; ga.wqp = wq;
  for (int i = 0; i < 8; i++) { ga.Wraw[i] = W[i]; ga.bias[i] = Bv[i]; }
  ga.wsc = wsc; ga.outs[0] = qf; ga.outs[1] = kf; ga.outs[2] = vf;
  ga.dout = d_out; ga.slots = slots; ga.flagp = flagp;

  if (do_prequant)
    gemm_f<0, 1><<<dim3(16, 18, 3), 256, 0, stream>>>(ga);
  else
    gemm_f<0, 0><<<dim3(16, 18, 3), 256, 0, stream>>>(ga);

  rms_absmax_v_k<<<256, 1024, 0, stream>>>(qf, kf, vf, nq, naq, nk, nak, slots, flagp);
  rope2_k<<<1024, 256, 0, stream>>>(qf, kf, cosb, sinb, slots, qb, kb, flagp);
  quant_transpose_v_k<<<dim3(SEQ / 64, DH / 64, NH), 256, 0, stream>>>(vf, slots, vtb);

  if (do_split) {
    flash_attn_k<1><<<dim3(SEQ / 64, NH, NSPLIT), 256, 0, stream>>>(qb, kb, vtb, nullptr,
                                                                    Opart, Mpart, Lpart);
    flash_combine_k<<<288, 1024, 0, stream>>>(Opart, Mpart, Lpart, attnf, slots + 8 * SSTR);
  } else {
    flash_attn_k<0><<<dim3(SEQ / 64, NH), 256, 0, stream>>>(qb, kb, vtb, attnf,
                                                            nullptr, nullptr, nullptr);
    absmax_f32_k<<<256, 256, 0, stream>>>(attnf, SEQ * DM, slots + 8 * SSTR);
  }
  quant_f32x8_k<<<1024, 256, 0, stream>>>(attnf, SEQ * DM / 8, slots + 8 * SSTR, attnq);

  if (do_prequant)
    gemm_f<1, 1><<<dim3(16, 18), 256, 0, stream>>>(ga);
  else
    gemm_f<1, 0><<<dim3(16, 18), 256, 0, stream>>>(ga);
}

// Round 6
// 718.476 us; speedup vs baseline: 1.0411x; 1.0411x over previous
//
#include <hip/hip_runtime.h>

// ===== Problem constants =====
constexpr int L_TXT = 256, L_IMG = 2048, SEQ = 2304;
constexpr int DM = 2048, NH = 16, DH = 128;
constexpr int NSPLIT = 4;      // flash split-K factor
constexpr int SSTR = 32;       // slot stride in unsigneds (128 B) - avoids atomic cacheline ping-pong

typedef __attribute__((ext_vector_type(8))) __bf16 bf16x8;
typedef __attribute__((ext_vector_type(4))) float f32x4;

// Runtime dtype flag: 0 = fp32 storage, 1 = bf16 (detected from rope_cos[0]).
__device__ __forceinline__ float ldin(const void* p, size_t i, int bf) {
  return bf ? (float)((const __bf16*)p)[i] : ((const float*)p)[i];
}
__device__ __forceinline__ float slot_scale(const unsigned* s) {
  return fmaxf(__uint_as_float(*s) / 127.0f, 1e-8f);
}
__device__ __forceinline__ float qclamp(float x, float sc) {
  float q = rintf(x / sc);     // RNE, matches jnp.round
  return fminf(fmaxf(q, -127.0f), 127.0f);
}
__device__ __forceinline__ float block_allmax_n(float v) {  // any blockDim multiple of 64 (<=1024)
  #pragma unroll
  for (int off = 32; off; off >>= 1) v = fmaxf(v, __shfl_xor(v, off));
  __shared__ float sm[16];
  int nw = blockDim.x >> 6;
  __syncthreads();
  if ((threadIdx.x & 63) == 0) sm[threadIdx.x >> 6] = v;
  __syncthreads();
  float m = sm[0];
  for (int i = 1; i < nw; i++) m = fmaxf(m, sm[i]);
  return m;
}

__global__ void detect_k(const void* cosp, int* flag) {
  if (threadIdx.x == 0) *flag = (((const unsigned short*)cosp)[0] != 0) ? 1 : 0;
}

struct Ptrs8 { const void* p[8]; };

// ===== Weight quantization (vectorized): scales + int-grid bf16 weights =====
__global__ void quant_weights_k(Ptrs8 win, __bf16* __restrict__ wq, float* __restrict__ scales,
                                const int* __restrict__ flagp) {
  const int bf = *flagp;
  int row = blockIdx.x, mat = blockIdx.y, t = threadIdx.x;
  float v[8];
  if (bf) {
    union { int4 q; __bf16 h[8]; } u;
    u.q = ((const int4*)((const __bf16*)win.p[mat] + (size_t)row * DM))[t];
    #pragma unroll
    for (int j = 0; j < 8; j++) v[j] = (float)u.h[j];
  } else {
    const float4* p = (const float4*)((const float*)win.p[mat] + (size_t)row * DM);
    float4 a = p[t * 2], b = p[t * 2 + 1];
    v[0]=a.x; v[1]=a.y; v[2]=a.z; v[3]=a.w; v[4]=b.x; v[5]=b.y; v[6]=b.z; v[7]=b.w;
  }
  float m = 0.f;
  #pragma unroll
  for (int j = 0; j < 8; j++) m = fmaxf(m, fabsf(v[j]));
  m = block_allmax_n(m);
  float sc = fmaxf(m / 127.0f, 1e-8f);
  if (t == 0) scales[mat * DM + row] = sc;
  union { int4 q; __bf16 h[8]; } o;
  #pragma unroll
  for (int j = 0; j < 8; j++) o.h[j] = (__bf16)qclamp(v[j], sc);
  ((int4*)(wq + (size_t)mat * DM * DM + (size_t)row * DM))[t] = o.q;
}
// fallback: scales only
__global__ void weight_scales_k(Ptrs8 win, float* __restrict__ scales, const int* __restrict__ flagp) {
  const int bf = *flagp;
  int row = blockIdx.x, mat = blockIdx.y, t = threadIdx.x;
  float m = 0.f;
  for (int c = t; c < DM; c += 256) m = fmaxf(m, fabsf(ldin(win.p[mat], (size_t)row * DM + c, bf)));
  m = block_allmax_n(m);
  if (t == 0) scales[mat * DM + row] = fmaxf(m / 127.0f, 1e-8f);
}

// ===== absmax of hidden + encoder in one pass (vectorized x8) =====
__global__ void absmax_he_k(const void* __restrict__ hs, const void* __restrict__ es,
                            unsigned* s0, unsigned* s1, const int* __restrict__ flagp) {
  const int bf = *flagp;
  const int n18 = L_IMG * DM / 8, n28 = L_TXT * DM / 8;
  float m1 = 0.f, m2 = 0.f;
  for (int i = blockIdx.x * 256 + threadIdx.x; i < n18 + n28; i += gridDim.x * 256) {
    bool h = i < n18;
    const void* src = h ? hs : es;
    int j = h ? i : i - n18;
    float lm = 0.f;
    if (bf) {
      union { int4 q; __bf16 x[8]; } u; u.q = ((const int4*)src)[j];
      #pragma unroll
      for (int k = 0; k < 8; k++) lm = fmaxf(lm, fabsf((float)u.x[k]));
    } else {
      const float4* p = (const float4*)src;
      float4 a = p[j * 2], b = p[j * 2 + 1];
      lm = fmaxf(fmaxf(fmaxf(fabsf(a.x), fabsf(a.y)), fmaxf(fabsf(a.z), fabsf(a.w))),
                 fmaxf(fmaxf(fabsf(b.x), fabsf(b.y)), fmaxf(fabsf(b.z), fabsf(b.w))));
    }
    if (h) m1 = fmaxf(m1, lm); else m2 = fmaxf(m2, lm);
  }
  m1 = block_allmax_n(m1);
  __syncthreads();
  m2 = block_allmax_n(m2);
  if (threadIdx.x == 0) { atomicMax(s0, __float_as_uint(m1)); atomicMax(s1, __float_as_uint(m2)); }
}

// ===== quantize hidden+encoder to int-grid bf16 (vectorized x8) =====
__global__ void quant_he_k(const void* __restrict__ hs, const void* __restrict__ es,
                           const unsigned* __restrict__ slots, __bf16* __restrict__ hqo,
                           __bf16* __restrict__ eqo, const int* __restrict__ flagp) {
  const int bf = *flagp;
  const int n18 = L_IMG * DM / 8, n28 = L_TXT * DM / 8;
  float sc0 = slot_scale(slots), sc1 = slot_scale(slots + SSTR);
  for (int i = blockIdx.x * 256 + threadIdx.x; i < n18 + n28; i += gridDim.x * 256) {
    bool h = i < n18;
    const void* src = h ? hs : es;
    int j = h ? i : i - n18;
    float sc = h ? sc0 : sc1;
    float v[8];
    if (bf) {
      union { int4 q; __bf16 x[8]; } u; u.q = ((const int4*)src)[j];
      #pragma unroll
      for (int k = 0; k < 8; k++) v[k] = (float)u.x[k];
    } else {
      const float4* p = (const float4*)src;
      float4 a = p[j * 2], b = p[j * 2 + 1];
      v[0]=a.x; v[1]=a.y; v[2]=a.z; v[3]=a.w; v[4]=b.x; v[5]=b.y; v[6]=b.z; v[7]=b.w;
    }
    union { int4 q; __bf16 x[8]; } o;
    #pragma unroll
    for (int k = 0; k < 8; k++) o.x[k] = (__bf16)qclamp(v[k], sc);
    ((int4*)(h ? hqo : eqo))[j] = o.q;
  }
}

// ===== quantize fp32 attn-out to int-grid bf16 (vectorized x8) =====
__global__ void quant_f32x8_k(const float* __restrict__ x, int n8,
                              const unsigned* __restrict__ slot, __bf16* __restrict__ out) {
  float sc = slot_scale(slot);
  for (int i = blockIdx.x * 256 + threadIdx.x; i < n8; i += gridDim.x * 256) {
    float4 a = ((const float4*)x)[i * 2], b = ((const float4*)x)[i * 2 + 1];
    union { int4 q; __bf16 h[8]; } o;
    o.h[0]=(__bf16)qclamp(a.x,sc); o.h[1]=(__bf16)qclamp(a.y,sc);
    o.h[2]=(__bf16)qclamp(a.z,sc); o.h[3]=(__bf16)qclamp(a.w,sc);
    o.h[4]=(__bf16)qclamp(b.x,sc); o.h[5]=(__bf16)qclamp(b.y,sc);
    o.h[6]=(__bf16)qclamp(b.z,sc); o.h[7]=(__bf16)qclamp(b.w,sc);
    ((int4*)out)[i] = o.q;
  }
}
// fallback absmax (non-split flash path)
__global__ void absmax_f32_k(const float* __restrict__ x, int n, unsigned* slot) {
  float m = 0.f;
  for (int i = blockIdx.x * 256 + threadIdx.x; i < n; i += gridDim.x * 256)
    m = fmaxf(m, fabsf(x[i]));
  m = block_allmax_n(m);
  if (threadIdx.x == 0) atomicMax(slot, __float_as_uint(m));
}

// ===== fused: rmsnorm(q)+absmax, rmsnorm(k)+absmax, absmax(v) =====
__global__ void rms_absmax_v_k(float* __restrict__ qf, float* __restrict__ kf, float* __restrict__ vf,
                               const void* nq, const void* naq, const void* nk, const void* nak,
                               unsigned* __restrict__ slots, const int* __restrict__ flagp) {
  const int bf = *flagp;
  const int t = threadIdx.x, lane = t & 63, wave = t >> 6;   // 1024 thr = 16 waves
  float wqt0 = ldin(naq, lane, bf), wqt1 = ldin(naq, lane + 64, bf);
  float wqi0 = ldin(nq,  lane, bf), wqi1 = ldin(nq,  lane + 64, bf);
  float wkt0 = ldin(nak, lane, bf), wkt1 = ldin(nak, lane + 64, bf);
  float wki0 = ldin(nk,  lane, bf), wki1 = ldin(nk,  lane + 64, bf);
  const int NR = NH * SEQ;
  float mx[6] = {0.f, 0.f, 0.f, 0.f, 0.f, 0.f};
  for (int row = blockIdx.x * 16 + wave; row < 3 * NR; row += gridDim.x * 16) {
    int tns = row / NR, r2 = row - tns * NR;
    int s = r2 % SEQ; bool txt = s < L_TXT;
    float* p = (tns == 0 ? qf : tns == 1 ? kf : vf) + (size_t)r2 * DH;
    float v0 = p[lane], v1 = p[lane + 64];
    if (tns < 2) {
      float ss = v0 * v0 + v1 * v1;
      #pragma unroll
      for (int off = 32; off; off >>= 1) ss += __shfl_xor(ss, off);
      float r = rsqrtf(ss * (1.0f / 128.0f) + 1e-6f);
      float w0, w1;
      if (tns == 0) { w0 = txt ? wqt0 : wqi0; w1 = txt ? wqt1 : wqi1; }
      else          { w0 = txt ? wkt0 : wki0; w1 = txt ? wkt1 : wki1; }
      v0 *= r * w0; v1 *= r * w1;
      p[lane] = v0; p[lane + 64] = v1;
    }
    int idx = tns * 2 + (txt ? 0 : 1);
    mx[idx] = fmaxf(mx[idx], fmaxf(fabsf(v0), fabsf(v1)));
  }
  #pragma unroll
  for (int off = 32; off; off >>= 1)
    #pragma unroll
    for (int j = 0; j < 6; j++) mx[j] = fmaxf(mx[j], __shfl_xor(mx[j], off));
  __shared__ float smx[16][6];
  if (lane == 0)
    #pragma unroll
    for (int j = 0; j < 6; j++) smx[wave][j] = mx[j];
  __syncthreads();
  if (t == 0) {
    #pragma unroll
    for (int j = 0; j < 6; j++) {
      float m = smx[0][j];
      for (int i = 1; i < 16; i++) m = fmaxf(m, smx[i][j]);
      atomicMax(slots + (2 + j) * SSTR, __float_as_uint(m));
    }
  }
}

// ===== fused rope for q and k: quantize (dequant) + rotate + bf16 =====
__global__ void rope2_k(const float* __restrict__ qf, const float* __restrict__ kf,
                        const void* cosb, const void* sinb, const unsigned* __restrict__ slots,
                        __bf16* __restrict__ qb, __bf16* __restrict__ kb, const int* __restrict__ flagp) {
  const int bf = *flagp;
  const int NP = NH * SEQ * 64;
  for (int i = blockIdx.x * 256 + threadIdx.x; i < 2 * NP; i += gridDim.x * 256) {
    int tns = i >= NP;
    int j = i - tns * NP;
    int pr = j & 63, rowg = j >> 6;
    int s = rowg % SEQ;
    const float* src = tns ? kf : qf;
    __bf16* dst = tns ? kb : qb;
    float sc = slot_scale(slots + (tns ? 4 : 2) * SSTR + (s < L_TXT ? 0 : SSTR));
    size_t base = (size_t)rowg * DH + pr * 2;
    float2 x2 = *(const float2*)(src + base);
    float q0 = qclamp(x2.x, sc) * sc, q1 = qclamp(x2.y, sc) * sc;
    float c0 = ldin(cosb, s * DH + 2 * pr, bf), c1 = ldin(cosb, s * DH + 2 * pr + 1, bf);
    float s0 = ldin(sinb, s * DH + 2 * pr, bf), s1 = ldin(sinb, s * DH + 2 * pr + 1, bf);
    dst[base]     = (__bf16)(q0 * c0 - q1 * s0);
    dst[base + 1] = (__bf16)(q1 * c1 + q0 * s1);
  }
}

// ===== V: quantize + transpose [NH][SEQ][DH] -> [NH][DH][SEQ] =====
__global__ void quant_transpose_v_k(const float* __restrict__ v, const unsigned* __restrict__ slots,
                                    __bf16* __restrict__ vt) {
  __shared__ float tile[64][65];
  int t = threadIdx.x;
  int s0 = blockIdx.x * 64, d0 = blockIdx.y * 64, h = blockIdx.z;
  #pragma unroll
  for (int i = 0; i < 16; i++) {
    int r = i * 4 + (t >> 6), c = t & 63;
    tile[r][c] = v[((size_t)(h * SEQ) + s0 + r) * DH + d0 + c];
  }
  __syncthreads();
  float sc = slot_scale(slots + (s0 < L_TXT ? 6 : 7) * SSTR);
  #pragma unroll
  for (int i = 0; i < 16; i++) {
    int d = i * 4 + (t >> 6), s = t & 63;
    float q = qclamp(tile[s][d], sc) * sc;
    vt[((size_t)(h * DH) + d0 + d) * SEQ + s0 + s] = (__bf16)q;
  }
}

// ===== GEMM (fused launches) =====
struct GemmArgs {
  const __bf16 *hq, *eq, *attnq;
  const __bf16* wqp;
  const void* Wraw[8];
  const float* wsc;
  const void* bias[8];
  float* outs[3];
  void* dout;
  const unsigned* slots;
  const int* flagp;
};
template<int MODE, int QW>
__global__ __launch_bounds__(256, 2)
void gemm_f(GemmArgs a) {
  const int bf = *a.flagp;
  constexpr int K = DM;
  __shared__ __bf16 As[128][72];
  __shared__ __bf16 Ws[128][72];
  const int t = threadIdx.x, lane = t & 63, wave = t >> 6;
  const int l15 = lane & 15, quad = lane >> 4;
  const int n0 = blockIdx.x * 128, y = blockIdx.y;
  int mat, outrow; const __bf16* A; const unsigned* aslot;
  if (MODE == 0) {
    bool txt = y < 2;
    mat = blockIdx.z + (txt ? 3 : 0);
    A = (txt ? a.eq : a.hq) + (size_t)(txt ? y * 128 : (y - 2) * 128) * K;
    outrow = y * 128;
    aslot = a.slots + (txt ? SSTR : 0);
  } else {
    bool img = y < 16;
    mat = img ? 6 : 7;
    A = a.attnq + (size_t)(img ? L_TXT + y * 128 : (y - 16) * 128) * K;
    outrow = img ? y * 128 : L_IMG + (y - 16) * 128;
    aslot = a.slots + 8 * SSTR;
  }
  const __bf16* Wq = QW ? a.wqp + (size_t)mat * DM * DM : nullptr;
  const void* Wr = a.Wraw[mat];
  const float* wrow = a.wsc + mat * DM;
  int wm = (wave & 1) * 64, wn = (wave >> 1) * 64;
  f32x4 acc[4][4] = {};
  int sr = t >> 3, sc = (t & 7) * 8;
  float wsc4[4];
  if (!QW) {
    #pragma unroll
    for (int p = 0; p < 4; p++) wsc4[p] = wrow[n0 + p * 32 + sr];
  }
  for (int k0 = 0; k0 < K; k0 += 64) {
    __syncthreads();
    #pragma unroll
    for (int p = 0; p < 4; p++) {
      int r = p * 32 + sr;
      *(int4*)&As[r][sc] = *(const int4*)&A[(size_t)r * K + k0 + sc];
      if (QW) {
        *(int4*)&Ws[r][sc] = *(const int4*)&Wq[(size_t)(n0 + r) * K + k0 + sc];
      } else {
        union { bf16x8 v; __bf16 h[8]; } q;
        if (bf) {
          union { int4 v; __bf16 h[8]; } u;
          u.v = *(const int4*)((const __bf16*)Wr + (size_t)(n0 + r) * K + k0 + sc);
          #pragma unroll
          for (int j = 0; j < 8; j++) q.h[j] = (__bf16)qclamp((float)u.h[j], wsc4[p]);
        } else {
          const float* wp = (const float*)Wr + (size_t)(n0 + r) * K + k0 + sc;
          float4 x = *(const float4*)wp, z = *(const float4*)(wp + 4);
          q.h[0]=(__bf16)qclamp(x.x,wsc4[p]); q.h[1]=(__bf16)qclamp(x.y,wsc4[p]);
          q.h[2]=(__bf16)qclamp(x.z,wsc4[p]); q.h[3]=(__bf16)qclamp(x.w,wsc4[p]);
          q.h[4]=(__bf16)qclamp(z.x,wsc4[p]); q.h[5]=(__bf16)qclamp(z.y,wsc4[p]);
          q.h[6]=(__bf16)qclamp(z.z,wsc4[p]); q.h[7]=(__bf16)qclamp(z.w,wsc4[p]);
        }
        *(bf16x8*)&Ws[r][sc] = q.v;
      }
    }
    __syncthreads();
    #pragma unroll
    for (int kk = 0; kk < 64; kk += 32) {
      bf16x8 af[4], bfr[4];
      #pragma unroll
      for (int i = 0; i < 4; i++) {
        af[i]  = *(const bf16x8*)&As[wm + i * 16 + l15][kk + quad * 8];
        bfr[i] = *(const bf16x8*)&Ws[wn + i * 16 + l15][kk + quad * 8];
      }
      #pragma unroll
      for (int i = 0; i < 4; i++)
        #pragma unroll
        for (int j = 0; j < 4; j++)
          acc[i][j] = __builtin_amdgcn_mfma_f32_16x16x32_bf16(af[i], bfr[j], acc[i][j], 0, 0, 0);
    }
  }
  float asc = slot_scale(aslot);
  #pragma unroll
  for (int j = 0; j < 4; j++) {
    int gn = n0 + wn + j * 16 + l15;
    float wsb = wrow[gn] * asc;
    float bv = ldin(a.bias[mat], gn, bf);
    #pragma unroll
    for (int i = 0; i < 4; i++)
      #pragma unroll
      for (int r = 0; r < 4; r++) {
        int gm = wm + i * 16 + quad * 4 + r;    // C/D: col=lane&15, row=quad*4+reg (m89)
        float val = acc[i][j][r] * wsb + bv;
        if (MODE == 0) {
          a.outs[blockIdx.z][(size_t)(gn >> 7) * (SEQ * DH) + (size_t)(outrow + gm) * DH + (gn & 127)] = val;
        } else {
          size_t idx = (size_t)(outrow + gm) * DM + gn;
          if (bf) ((__bf16*)a.dout)[idx] = (__bf16)val; else ((float*)a.dout)[idx] = val;
        }
      }
  }
}

// ===== Flash attention: Br=64 (4 waves x 16 rows), Bc=32, online softmax =====
// Round-11 (clean retry of round-10; round-10's bench died on an infra error
// "container failed twice" with no counters, and the echoed source had lost
// quant_he_k's sc0/sc1 declaration -- restored here).
// Rounds 7-9 post-mortem: ANY min-waves launch_bounds >=3 on this prefetch
// loop shape spills (~500 MB scratch WRITE each time) regardless of my
// enumeration (~92-110 live values vs 168 budget) -- the allocator
// software-pipelines the prefetch loads across the asm-barrier regions,
// inflating demand past the cap, and spills rather than de-pipeline. The two
// no-spill configs were R0 (no prefetch, (256,3)) and R1 (prefetch, (256,2)).
// Fix: REMOVE the min-waves clause entirely -- __launch_bounds__(256) only.
// With no cap the allocator never spills; occupancy follows true demand.
// If demand is ~100-130 as enumerated -> 3-4 waves/SIMD naturally (the goal);
// if the compiler takes >170 -> 2 waves/SIMD == R1's 181 us (bounded downside),
// and VGPR_Count finally reports the true demand for the next round's decision.
// R9's lean Bc=32 shape retained; prefetch, lgkm-only raw barriers, separate
// Ps (2 barriers/tile), fused softmax, setprio all retained.
template<int SPLIT>
__global__ __launch_bounds__(256)
void flash_attn_k(const __bf16* __restrict__ Qb, const __bf16* __restrict__ Kb,
                  const __bf16* __restrict__ Vt, float* __restrict__ O,
                  float* __restrict__ Op, float* __restrict__ Mp, float* __restrict__ Lp) {
  __shared__ __align__(16) char smem[9728 + 10240 + 5120];
  auto Ks = (__bf16(*)[152])smem;                  // 32 K-rows, stride 304 B
  auto Vs = (__bf16(*)[40])(smem + 9728);          // 128 d-rows, stride 80 B
  auto Ps = (__bf16(*)[40])(smem + 9728 + 10240);  // 64 q-rows, stride 80 B
  const int t = threadIdx.x, lane = t & 63, wave = t >> 6;
  const int l15 = lane & 15, quad = lane >> 4;
  const int h = blockIdx.y, s0 = blockIdx.x * 64, qr = wave * 16;
  const float fscale = 0.08838834764831845f * 1.4426950408889634f;  // sm_scale*log2e

  bf16x8 qf[4];
  #pragma unroll
  for (int kk = 0; kk < 4; kk++)
    qf[kk] = *(const bf16x8*)&Qb[(size_t)(h * SEQ + s0 + qr + l15) * DH + kk * 32 + quad * 8];

  f32x4 accO[8] = {};
  float m_st[4], l_st[4];
  #pragma unroll
  for (int r = 0; r < 4; r++) { m_st[r] = -1e30f; l_st[r] = 0.f; }

  const int NT = SEQ / 32;                       // 72 tiles
  const int ktb = SPLIT ? blockIdx.z * (NT / NSPLIT) : 0;
  const int kte = SPLIT ? ktb + (NT / NSPLIT) : NT;

  const int krr = t >> 4, krc = (t & 15) * 8;    // K staging: 2 x 16 rows, 128 cols
  const int vrr = t >> 2, vrc = (t & 3) * 8;     // V staging: 2 x 64 d-rows, 32 cols
  int4 kreg[2], vreg[2];
  #pragma unroll
  for (int p = 0; p < 2; p++) {
    kreg[p] = *(const int4*)&Kb[(size_t)(h * SEQ + ktb * 32 + p * 16 + krr) * DH + krc];
    vreg[p] = *(const int4*)&Vt[(size_t)(h * DH + p * 64 + vrr) * SEQ + ktb * 32 + vrc];
  }

  for (int kt = ktb; kt < kte; kt++) {
    // B1: all waves done reading Ks (QK of tile kt-1) and Vs (PV of kt-1).
    // lgkm-only drain: prefetch global loads stay in flight across the barrier.
    asm volatile("s_waitcnt lgkmcnt(0)" ::: "memory");
    __builtin_amdgcn_s_barrier();
    #pragma unroll
    for (int p = 0; p < 2; p++) {
      *(int4*)&Ks[p * 16 + krr][krc] = kreg[p];
      *(int4*)&Vs[p * 64 + vrr][vrc] = vreg[p];
    }
    if (kt + 1 < kte) {   // next tile's loads complete under this tile's compute
      #pragma unroll
      for (int p = 0; p < 2; p++) {
        kreg[p] = *(const int4*)&Kb[(size_t)(h * SEQ + (kt + 1) * 32 + p * 16 + krr) * DH + krc];
        vreg[p] = *(const int4*)&Vt[(size_t)(h * DH + p * 64 + vrr) * SEQ + (kt + 1) * 32 + vrc];
      }
    }
    // B2: staging visible.
    asm volatile("s_waitcnt lgkmcnt(0)" ::: "memory");
    __builtin_amdgcn_s_barrier();

    f32x4 accS[2] = {};
    __builtin_amdgcn_s_setprio(1);
    #pragma unroll
    for (int kk = 0; kk < 4; kk++)
      #pragma unroll
      for (int ni = 0; ni < 2; ni++) {
        bf16x8 bk = *(const bf16x8*)&Ks[ni * 16 + l15][kk * 32 + quad * 8];
        accS[ni] = __builtin_amdgcn_mfma_f32_16x16x32_bf16(qf[kk], bk, accS[ni], 0, 0, 0);
      }
    __builtin_amdgcn_s_setprio(0);

    // Fused softmax per output row r: rowmax -> alpha -> exp/sum -> rescale accO.
    #pragma unroll
    for (int r = 0; r < 4; r++) {
      float rm = fmaxf(accS[0][r], accS[1][r]);
      #pragma unroll
      for (int off = 8; off > 0; off >>= 1) rm = fmaxf(rm, __shfl_xor(rm, off));
      float mn = fmaxf(m_st[r], rm);
      float al = exp2f((m_st[r] - mn) * fscale);
      m_st[r] = mn;
      float rs = 0.f;
      #pragma unroll
      for (int ni = 0; ni < 2; ni++) {
        float pv = exp2f((accS[ni][r] - mn) * fscale);
        accS[ni][r] = pv;
        rs += pv;
      }
      #pragma unroll
      for (int off = 8; off > 0; off >>= 1) rs += __shfl_xor(rs, off);
      l_st[r] = l_st[r] * al + rs;
      #pragma unroll
      for (int di = 0; di < 8; di++)
        accO[di][r] *= al;
    }
    // Ps rows [qr, qr+16) are wave-private (separate buffer -- no barrier).
    #pragma unroll
    for (int ni = 0; ni < 2; ni++)
      #pragma unroll
      for (int r = 0; r < 4; r++)
        Ps[qr + quad * 4 + r][ni * 16 + l15] = (__bf16)accS[ni][r];
    // PV (K=32, single k-step): Ps same-wave RAW via compiler lgkmcnt; Vs stable since B2.
    __builtin_amdgcn_s_setprio(1);
    {
      bf16x8 pa = *(const bf16x8*)&Ps[qr + l15][quad * 8];
      #pragma unroll
      for (int di = 0; di < 8; di++) {
        bf16x8 vb = *(const bf16x8*)&Vs[di * 16 + l15][quad * 8];
        accO[di] = __builtin_amdgcn_mfma_f32_16x16x32_bf16(pa, vb, accO[di], 0, 0, 0);
      }
    }
    __builtin_amdgcn_s_setprio(0);
  }
  if (SPLIT) {
    const size_t SP = (size_t)NH * SEQ * DH;
    const int sp = blockIdx.z;
    #pragma unroll
    for (int r = 0; r < 4; r++) {
      int gs = s0 + qr + quad * 4 + r;
      size_t ib = sp * SP + ((size_t)h * SEQ + gs) * DH;
      if (l15 == 0) {
        Mp[(size_t)sp * NH * SEQ + h * SEQ + gs] = m_st[r];
        Lp[(size_t)sp * NH * SEQ + h * SEQ + gs] = l_st[r];
      }
      #pragma unroll
      for (int di = 0; di < 8; di++)
        Op[ib + di * 16 + l15] = accO[di][r];
    }
  } else {
    #pragma unroll
    for (int r = 0; r < 4; r++) {
      float inv = 1.0f / l_st[r];
      int gs = s0 + qr + quad * 4 + r;
      #pragma unroll
      for (int di = 0; di < 8; di++)
        O[(size_t)gs * DM + h * DH + di * 16 + l15] = accO[di][r] * inv;
    }
  }
}

// Merge NSPLIT partials + global absmax of result (feeds attn-out quant).
__global__ void flash_combine_k(const float* __restrict__ Op, const float* __restrict__ Mp,
                                const float* __restrict__ Lp, float* __restrict__ O,
                                unsigned* __restrict__ slot8) {
  const float fscale = 0.08838834764831845f * 1.4426950408889634f;
  const int t = threadIdx.x, lane = t & 63, w = t >> 6;   // 1024 thr, 16 waves
  const size_t SP = (size_t)NH * SEQ * DH, MR = (size_t)NH * SEQ;
  float lm = 0.f;
  for (int row = blockIdx.x * 16 + w; row < NH * SEQ; row += gridDim.x * 16) {
    float m0 = Mp[row], m1 = Mp[MR + row], m2 = Mp[2 * MR + row], m3 = Mp[3 * MR + row];
    float M = fmaxf(fmaxf(m0, m1), fmaxf(m2, m3));
    float w0 = exp2f((m0 - M) * fscale), w1 = exp2f((m1 - M) * fscale);
    float w2 = exp2f((m2 - M) * fscale), w3 = exp2f((m3 - M) * fscale);
    float inv = 1.0f / (Lp[row] * w0 + Lp[MR + row] * w1 + Lp[2 * MR + row] * w2 + Lp[3 * MR + row] * w3);
    int h = row / SEQ, s = row % SEQ;
    size_t ob = (size_t)s * DM + h * DH, ib = (size_t)row * DH;
    #pragma unroll
    for (int j = 0; j < 2; j++) {
      int d = lane + j * 64;
      float v = (Op[ib + d] * w0 + Op[SP + ib + d] * w1 +
                 Op[2 * SP + ib + d] * w2 + Op[3 * SP + ib + d] * w3) * inv;
      O[ob + d] = v;
      lm = fmaxf(lm, fabsf(v));
    }
  }
  lm = block_allmax_n(lm);
  if (t == 0) atomicMax(slot8, __float_as_uint(lm));
}

extern "C" void kernel_launch(void* const* d_in, const int* in_sizes, int n_in,
                              void* d_out, int out_size, void* d_ws, size_t ws_size,
                              hipStream_t stream) {
  (void)in_sizes; (void)n_in; (void)out_size;
  const void* hs   = d_in[0];
  const void* es   = d_in[1];
  const void* cosb = d_in[2];
  const void* sinb = d_in[3];
  const void* W[8]; const void* Bv[8];
  for (int i = 0; i < 8; i++) { W[i] = d_in[4 + 2 * i]; Bv[i] = d_in[5 + 2 * i]; }
  const void* nq  = d_in[20];
  const void* nk  = d_in[21];
  const void* naq = d_in[22];
  const void* nak = d_in[23];

  char* ws = (char*)d_ws;
  size_t off = 0;
  auto take = [&](size_t b) { char* p = ws + off; off += (b + 255) & ~(size_t)255; return p; };
  const size_t T = (size_t)NH * SEQ * DH * 4;      // 18.87 MB (one fp32 qkv tensor)

  unsigned* slots = (unsigned*)take(16 * SSTR * 4);   // 9 scale slots + flag, 128 B apart
  int* flagp = (int*)(slots + 15 * SSTR);
  float* wsc = (float*)take(8ull * DM * 4);

  size_t here = off;
  size_t need_base  = 4 * T + T + 3 * (T / 2) + 2 * ((size_t)NSPLIT * NH * SEQ * 4 + 256) + 1024;
  bool do_split = here + need_base <= ws_size;
  size_t region_sz = do_split ? 4 * T : 3 * T;

  char* region = take(region_sz);                  // qf,kf,vf; later Opart(+attnq)
  float* qf = (float*)region;
  float* kf = (float*)(region + T);
  float* vf = (float*)(region + 2 * T);
  float* Opart = (float*)region;
  __bf16* attnq = (__bf16*)region;                 // after combine (Opart dead)
  char* attnfR = take(T);                          // hq+eq early; attnf after flash
  __bf16* hq = (__bf16*)attnfR;
  __bf16* eq = (__bf16*)(attnfR + (size_t)L_IMG * DM * 2);
  float* attnf = (float*)attnfR;
  __bf16* qb  = (__bf16*)take(T / 2);
  __bf16* kb  = (__bf16*)take(T / 2);
  __bf16* vtb = (__bf16*)take(T / 2);
  float* Mpart = (float*)take((size_t)NSPLIT * NH * SEQ * 4);
  float* Lpart = (float*)take((size_t)NSPLIT * NH * SEQ * 4);
  bool do_prequant = (off + 8ull * DM * DM * 2 + 256 <= ws_size);
  __bf16* wq = do_prequant ? (__bf16*)take(8ull * DM * DM * 2) : nullptr;

  hipMemsetAsync(slots, 0, 16 * SSTR * 4, stream);
  detect_k<<<1, 64, 0, stream>>>(cosb, flagp);

  Ptrs8 win;
  for (int i = 0; i < 8; i++) win.p[i] = W[i];
  if (do_prequant)
    quant_weights_k<<<dim3(DM, 8), 256, 0, stream>>>(win, wq, wsc, flagp);
  else
    weight_scales_k<<<dim3(DM, 8), 256, 0, stream>>>(win, wsc, flagp);

  absmax_he_k<<<512, 256, 0, stream>>>(hs, es, slots, slots + SSTR, flagp);
  quant_he_k<<<1024, 256, 0, stream>>>(hs, es, slots, hq, eq, flagp);

  GemmArgs ga;
  ga.hq = hq; ga.eq = eq; ga.attnq = attnq; ga.wqp = wq;
  for (int i = 0; i < 8; i++) { ga.Wraw[i] = W[i]; ga.bias[i] = Bv[i]; }
  ga.wsc = wsc; ga.outs[0] = qf; ga.outs[1] = kf; ga.outs[2] = vf;
  ga.dout = d_out; ga.slots = slots; ga.flagp = flagp;

  if (do_prequant)
    gemm_f<0, 1><<<dim3(16, 18, 3), 256, 0, stream>>>(ga);
  else
    gemm_f<0, 0><<<dim3(16, 18, 3), 256, 0, stream>>>(ga);

  rms_absmax_v_k<<<256, 1024, 0, stream>>>(qf, kf, vf, nq, naq, nk, nak, slots, flagp);
  rope2_k<<<1024, 256, 0, stream>>>(qf, kf, cosb, sinb, slots, qb, kb, flagp);
  quant_transpose_v_k<<<dim3(SEQ / 64, DH / 64, NH), 256, 0, stream>>>(vf, slots, vtb);

  if (do_split) {
    flash_attn_k<1><<<dim3(SEQ / 64, NH, NSPLIT), 256, 0, stream>>>(qb, kb, vtb, nullptr,
                                                                    Opart, Mpart, Lpart);
    flash_combine_k<<<288, 1024, 0, stream>>>(Opart, Mpart, Lpart, attnf, slots + 8 * SSTR);
  } else {
    flash_attn_k<0><<<dim3(SEQ / 64, NH), 256, 0, stream>>>(qb, kb, vtb, attnf,
                                                            nullptr, nullptr, nullptr);
    absmax_f32_k<<<256, 256, 0, stream>>>(attnf, SEQ * DM, slots + 8 * SSTR);
  }
  quant_f32x8_k<<<1024, 256, 0, stream>>>(attnf, SEQ * DM / 8, slots + 8 * SSTR, attnq);

  if (do_prequant)
    gemm_f<1, 1><<<dim3(16, 18), 256, 0, stream>>>(ga);
  else
    gemm_f<1, 0><<<dim3(16, 18), 256, 0, stream>>>(ga);
}

// Round 7
// 652.954 us; speedup vs baseline: 1.1455x; 1.1003x over previous
//
#include <hip/hip_runtime.h>

// ===== Problem constants =====
constexpr int L_TXT = 256, L_IMG = 2048, SEQ = 2304;
constexpr int DM = 2048, NH = 16, DH = 128;
constexpr int NSPLIT = 4;      // flash split-K factor
constexpr int SSTR = 32;       // slot stride in unsigneds (128 B) - avoids atomic cacheline ping-pong

typedef __attribute__((ext_vector_type(8))) __bf16 bf16x8;
typedef __attribute__((ext_vector_type(4))) float f32x4;

// Runtime dtype flag: 0 = fp32 storage, 1 = bf16 (detected from rope_cos[0]).
__device__ __forceinline__ float ldin(const void* p, size_t i, int bf) {
  return bf ? (float)((const __bf16*)p)[i] : ((const float*)p)[i];
}
__device__ __forceinline__ float slot_scale(const unsigned* s) {
  return fmaxf(__uint_as_float(*s) / 127.0f, 1e-8f);
}
__device__ __forceinline__ float qclamp(float x, float sc) {
  float q = rintf(x / sc);     // RNE, matches jnp.round
  return fminf(fmaxf(q, -127.0f), 127.0f);
}
// Direct global->LDS DMA, 16 B per lane. LDS dest = wave-uniform base + lane*16.
__device__ __forceinline__ void gload_lds16(const void* g, void* l) {
  __builtin_amdgcn_global_load_lds(
      (const __attribute__((address_space(1))) unsigned int*)g,
      (__attribute__((address_space(3))) unsigned int*)l, 16, 0, 0);
}
__device__ __forceinline__ float block_allmax_n(float v) {  // any blockDim multiple of 64 (<=1024)
  #pragma unroll
  for (int off = 32; off; off >>= 1) v = fmaxf(v, __shfl_xor(v, off));
  __shared__ float sm[16];
  int nw = blockDim.x >> 6;
  __syncthreads();
  if ((threadIdx.x & 63) == 0) sm[threadIdx.x >> 6] = v;
  __syncthreads();
  float m = sm[0];
  for (int i = 1; i < nw; i++) m = fmaxf(m, sm[i]);
  return m;
}

__global__ void detect_k(const void* cosp, int* flag) {
  if (threadIdx.x == 0) *flag = (((const unsigned short*)cosp)[0] != 0) ? 1 : 0;
}

struct Ptrs8 { const void* p[8]; };

// ===== Weight quantization (vectorized): scales + int-grid bf16 weights =====
__global__ void quant_weights_k(Ptrs8 win, __bf16* __restrict__ wq, float* __restrict__ scales,
                                const int* __restrict__ flagp) {
  const int bf = *flagp;
  int row = blockIdx.x, mat = blockIdx.y, t = threadIdx.x;
  float v[8];
  if (bf) {
    union { int4 q; __bf16 h[8]; } u;
    u.q = ((const int4*)((const __bf16*)win.p[mat] + (size_t)row * DM))[t];
    #pragma unroll
    for (int j = 0; j < 8; j++) v[j] = (float)u.h[j];
  } else {
    const float4* p = (const float4*)((const float*)win.p[mat] + (size_t)row * DM);
    float4 a = p[t * 2], b = p[t * 2 + 1];
    v[0]=a.x; v[1]=a.y; v[2]=a.z; v[3]=a.w; v[4]=b.x; v[5]=b.y; v[6]=b.z; v[7]=b.w;
  }
  float m = 0.f;
  #pragma unroll
  for (int j = 0; j < 8; j++) m = fmaxf(m, fabsf(v[j]));
  m = block_allmax_n(m);
  float sc = fmaxf(m / 127.0f, 1e-8f);
  if (t == 0) scales[mat * DM + row] = sc;
  union { int4 q; __bf16 h[8]; } o;
  #pragma unroll
  for (int j = 0; j < 8; j++) o.h[j] = (__bf16)qclamp(v[j], sc);
  ((int4*)(wq + (size_t)mat * DM * DM + (size_t)row * DM))[t] = o.q;
}
// fallback: scales only
__global__ void weight_scales_k(Ptrs8 win, float* __restrict__ scales, const int* __restrict__ flagp) {
  const int bf = *flagp;
  int row = blockIdx.x, mat = blockIdx.y, t = threadIdx.x;
  float m = 0.f;
  for (int c = t; c < DM; c += 256) m = fmaxf(m, fabsf(ldin(win.p[mat], (size_t)row * DM + c, bf)));
  m = block_allmax_n(m);
  if (t == 0) scales[mat * DM + row] = fmaxf(m / 127.0f, 1e-8f);
}

// ===== absmax of hidden + encoder in one pass (vectorized x8) =====
__global__ void absmax_he_k(const void* __restrict__ hs, const void* __restrict__ es,
                            unsigned* s0, unsigned* s1, const int* __restrict__ flagp) {
  const int bf = *flagp;
  const int n18 = L_IMG * DM / 8, n28 = L_TXT * DM / 8;
  float m1 = 0.f, m2 = 0.f;
  for (int i = blockIdx.x * 256 + threadIdx.x; i < n18 + n28; i += gridDim.x * 256) {
    bool h = i < n18;
    const void* src = h ? hs : es;
    int j = h ? i : i - n18;
    float lm = 0.f;
    if (bf) {
      union { int4 q; __bf16 x[8]; } u; u.q = ((const int4*)src)[j];
      #pragma unroll
      for (int k = 0; k < 8; k++) lm = fmaxf(lm, fabsf((float)u.x[k]));
    } else {
      const float4* p = (const float4*)src;
      float4 a = p[j * 2], b = p[j * 2 + 1];
      lm = fmaxf(fmaxf(fmaxf(fabsf(a.x), fabsf(a.y)), fmaxf(fabsf(a.z), fabsf(a.w))),
                 fmaxf(fmaxf(fabsf(b.x), fabsf(b.y)), fmaxf(fabsf(b.z), fabsf(b.w))));
    }
    if (h) m1 = fmaxf(m1, lm); else m2 = fmaxf(m2, lm);
  }
  m1 = block_allmax_n(m1);
  __syncthreads();
  m2 = block_allmax_n(m2);
  if (threadIdx.x == 0) { atomicMax(s0, __float_as_uint(m1)); atomicMax(s1, __float_as_uint(m2)); }
}

// ===== quantize hidden+encoder to int-grid bf16 (vectorized x8) =====
__global__ void quant_he_k(const void* __restrict__ hs, const void* __restrict__ es,
                           const unsigned* __restrict__ slots, __bf16* __restrict__ hqo,
                           __bf16* __restrict__ eqo, const int* __restrict__ flagp) {
  const int bf = *flagp;
  const int n18 = L_IMG * DM / 8, n28 = L_TXT * DM / 8;
  float sc0 = slot_scale(slots), sc1 = slot_scale(slots + SSTR);
  for (int i = blockIdx.x * 256 + threadIdx.x; i < n18 + n28; i += gridDim.x * 256) {
    bool h = i < n18;
    const void* src = h ? hs : es;
    int j = h ? i : i - n18;
    float sc = h ? sc0 : sc1;
    float v[8];
    if (bf) {
      union { int4 q; __bf16 x[8]; } u; u.q = ((const int4*)src)[j];
      #pragma unroll
      for (int k = 0; k < 8; k++) v[k] = (float)u.x[k];
    } else {
      const float4* p = (const float4*)src;
      float4 a = p[j * 2], b = p[j * 2 + 1];
      v[0]=a.x; v[1]=a.y; v[2]=a.z; v[3]=a.w; v[4]=b.x; v[5]=b.y; v[6]=b.z; v[7]=b.w;
    }
    union { int4 q; __bf16 x[8]; } o;
    #pragma unroll
    for (int k = 0; k < 8; k++) o.x[k] = (__bf16)qclamp(v[k], sc);
    ((int4*)(h ? hqo : eqo))[j] = o.q;
  }
}

// ===== quantize fp32 attn-out to int-grid bf16 (vectorized x8) =====
__global__ void quant_f32x8_k(const float* __restrict__ x, int n8,
                              const unsigned* __restrict__ slot, __bf16* __restrict__ out) {
  float sc = slot_scale(slot);
  for (int i = blockIdx.x * 256 + threadIdx.x; i < n8; i += gridDim.x * 256) {
    float4 a = ((const float4*)x)[i * 2], b = ((const float4*)x)[i * 2 + 1];
    union { int4 q; __bf16 h[8]; } o;
    o.h[0]=(__bf16)qclamp(a.x,sc); o.h[1]=(__bf16)qclamp(a.y,sc);
    o.h[2]=(__bf16)qclamp(a.z,sc); o.h[3]=(__bf16)qclamp(a.w,sc);
    o.h[4]=(__bf16)qclamp(b.x,sc); o.h[5]=(__bf16)qclamp(b.y,sc);
    o.h[6]=(__bf16)qclamp(b.z,sc); o.h[7]=(__bf16)qclamp(b.w,sc);
    ((int4*)out)[i] = o.q;
  }
}
// fallback absmax (non-split flash path)
__global__ void absmax_f32_k(const float* __restrict__ x, int n, unsigned* slot) {
  float m = 0.f;
  for (int i = blockIdx.x * 256 + threadIdx.x; i < n; i += gridDim.x * 256)
    m = fmaxf(m, fabsf(x[i]));
  m = block_allmax_n(m);
  if (threadIdx.x == 0) atomicMax(slot, __float_as_uint(m));
}

// ===== fused: rmsnorm(q)+absmax, rmsnorm(k)+absmax, absmax(v) =====
__global__ void rms_absmax_v_k(float* __restrict__ qf, float* __restrict__ kf, float* __restrict__ vf,
                               const void* nq, const void* naq, const void* nk, const void* nak,
                               unsigned* __restrict__ slots, const int* __restrict__ flagp) {
  const int bf = *flagp;
  const int t = threadIdx.x, lane = t & 63, wave = t >> 6;   // 1024 thr = 16 waves
  float wqt0 = ldin(naq, lane, bf), wqt1 = ldin(naq, lane + 64, bf);
  float wqi0 = ldin(nq,  lane, bf), wqi1 = ldin(nq,  lane + 64, bf);
  float wkt0 = ldin(nak, lane, bf), wkt1 = ldin(nak, lane + 64, bf);
  float wki0 = ldin(nk,  lane, bf), wki1 = ldin(nk,  lane + 64, bf);
  const int NR = NH * SEQ;
  float mx[6] = {0.f, 0.f, 0.f, 0.f, 0.f, 0.f};
  for (int row = blockIdx.x * 16 + wave; row < 3 * NR; row += gridDim.x * 16) {
    int tns = row / NR, r2 = row - tns * NR;
    int s = r2 % SEQ; bool txt = s < L_TXT;
    float* p = (tns == 0 ? qf : tns == 1 ? kf : vf) + (size_t)r2 * DH;
    float v0 = p[lane], v1 = p[lane + 64];
    if (tns < 2) {
      float ss = v0 * v0 + v1 * v1;
      #pragma unroll
      for (int off = 32; off; off >>= 1) ss += __shfl_xor(ss, off);
      float r = rsqrtf(ss * (1.0f / 128.0f) + 1e-6f);
      float w0, w1;
      if (tns == 0) { w0 = txt ? wqt0 : wqi0; w1 = txt ? wqt1 : wqi1; }
      else          { w0 = txt ? wkt0 : wki0; w1 = txt ? wkt1 : wki1; }
      v0 *= r * w0; v1 *= r * w1;
      p[lane] = v0; p[lane + 64] = v1;
    }
    int idx = tns * 2 + (txt ? 0 : 1);
    mx[idx] = fmaxf(mx[idx], fmaxf(fabsf(v0), fabsf(v1)));
  }
  #pragma unroll
  for (int off = 32; off; off >>= 1)
    #pragma unroll
    for (int j = 0; j < 6; j++) mx[j] = fmaxf(mx[j], __shfl_xor(mx[j], off));
  __shared__ float smx[16][6];
  if (lane == 0)
    #pragma unroll
    for (int j = 0; j < 6; j++) smx[wave][j] = mx[j];
  __syncthreads();
  if (t == 0) {
    #pragma unroll
    for (int j = 0; j < 6; j++) {
      float m = smx[0][j];
      for (int i = 1; i < 16; i++) m = fmaxf(m, smx[i][j]);
      atomicMax(slots + (2 + j) * SSTR, __float_as_uint(m));
    }
  }
}

// ===== fused rope for q and k: quantize (dequant) + rotate + bf16 =====
__global__ void rope2_k(const float* __restrict__ qf, const float* __restrict__ kf,
                        const void* cosb, const void* sinb, const unsigned* __restrict__ slots,
                        __bf16* __restrict__ qb, __bf16* __restrict__ kb, const int* __restrict__ flagp) {
  const int bf = *flagp;
  const int NP = NH * SEQ * 64;
  for (int i = blockIdx.x * 256 + threadIdx.x; i < 2 * NP; i += gridDim.x * 256) {
    int tns = i >= NP;
    int j = i - tns * NP;
    int pr = j & 63, rowg = j >> 6;
    int s = rowg % SEQ;
    const float* src = tns ? kf : qf;
    __bf16* dst = tns ? kb : qb;
    float sc = slot_scale(slots + (tns ? 4 : 2) * SSTR + (s < L_TXT ? 0 : SSTR));
    size_t base = (size_t)rowg * DH + pr * 2;
    float2 x2 = *(const float2*)(src + base);
    float q0 = qclamp(x2.x, sc) * sc, q1 = qclamp(x2.y, sc) * sc;
    float c0 = ldin(cosb, s * DH + 2 * pr, bf), c1 = ldin(cosb, s * DH + 2 * pr + 1, bf);
    float s0 = ldin(sinb, s * DH + 2 * pr, bf), s1 = ldin(sinb, s * DH + 2 * pr + 1, bf);
    dst[base]     = (__bf16)(q0 * c0 - q1 * s0);
    dst[base + 1] = (__bf16)(q1 * c1 + q0 * s1);
  }
}

// ===== V: quantize + transpose [NH][SEQ][DH] -> [NH][DH][SEQ] =====
__global__ void quant_transpose_v_k(const float* __restrict__ v, const unsigned* __restrict__ slots,
                                    __bf16* __restrict__ vt) {
  __shared__ float tile[64][65];
  int t = threadIdx.x;
  int s0 = blockIdx.x * 64, d0 = blockIdx.y * 64, h = blockIdx.z;
  #pragma unroll
  for (int i = 0; i < 16; i++) {
    int r = i * 4 + (t >> 6), c = t & 63;
    tile[r][c] = v[((size_t)(h * SEQ) + s0 + r) * DH + d0 + c];
  }
  __syncthreads();
  float sc = slot_scale(slots + (s0 < L_TXT ? 6 : 7) * SSTR);
  #pragma unroll
  for (int i = 0; i < 16; i++) {
    int d = i * 4 + (t >> 6), s = t & 63;
    float q = qclamp(tile[s][d], sc) * sc;
    vt[((size_t)(h * DH) + d0 + d) * SEQ + s0 + s] = (__bf16)q;
  }
}

// ===== GEMM (fused launches) =====
struct GemmArgs {
  const __bf16 *hq, *eq, *attnq;
  const __bf16* wqp;
  const void* Wraw[8];
  const float* wsc;
  const void* bias[8];
  float* outs[3];
  void* dout;
  const unsigned* slots;
  const int* flagp;
};
template<int MODE, int QW>
__global__ __launch_bounds__(256, 2)
void gemm_f(GemmArgs a) {
  const int bf = *a.flagp;
  constexpr int K = DM;
  __shared__ __bf16 As[128][72];
  __shared__ __bf16 Ws[128][72];
  const int t = threadIdx.x, lane = t & 63, wave = t >> 6;
  const int l15 = lane & 15, quad = lane >> 4;
  const int n0 = blockIdx.x * 128, y = blockIdx.y;
  int mat, outrow; const __bf16* A; const unsigned* aslot;
  if (MODE == 0) {
    bool txt = y < 2;
    mat = blockIdx.z + (txt ? 3 : 0);
    A = (txt ? a.eq : a.hq) + (size_t)(txt ? y * 128 : (y - 2) * 128) * K;
    outrow = y * 128;
    aslot = a.slots + (txt ? SSTR : 0);
  } else {
    bool img = y < 16;
    mat = img ? 6 : 7;
    A = a.attnq + (size_t)(img ? L_TXT + y * 128 : (y - 16) * 128) * K;
    outrow = img ? y * 128 : L_IMG + (y - 16) * 128;
    aslot = a.slots + 8 * SSTR;
  }
  const __bf16* Wq = QW ? a.wqp + (size_t)mat * DM * DM : nullptr;
  const void* Wr = a.Wraw[mat];
  const float* wrow = a.wsc + mat * DM;
  int wm = (wave & 1) * 64, wn = (wave >> 1) * 64;
  f32x4 acc[4][4] = {};
  int sr = t >> 3, sc = (t & 7) * 8;
  float wsc4[4];
  if (!QW) {
    #pragma unroll
    for (int p = 0; p < 4; p++) wsc4[p] = wrow[n0 + p * 32 + sr];
  }
  for (int k0 = 0; k0 < K; k0 += 64) {
    __syncthreads();
    #pragma unroll
    for (int p = 0; p < 4; p++) {
      int r = p * 32 + sr;
      *(int4*)&As[r][sc] = *(const int4*)&A[(size_t)r * K + k0 + sc];
      if (QW) {
        *(int4*)&Ws[r][sc] = *(const int4*)&Wq[(size_t)(n0 + r) * K + k0 + sc];
      } else {
        union { bf16x8 v; __bf16 h[8]; } q;
        if (bf) {
          union { int4 v; __bf16 h[8]; } u;
          u.v = *(const int4*)((const __bf16*)Wr + (size_t)(n0 + r) * K + k0 + sc);
          #pragma unroll
          for (int j = 0; j < 8; j++) q.h[j] = (__bf16)qclamp((float)u.h[j], wsc4[p]);
        } else {
          const float* wp = (const float*)Wr + (size_t)(n0 + r) * K + k0 + sc;
          float4 x = *(const float4*)wp, z = *(const float4*)(wp + 4);
          q.h[0]=(__bf16)qclamp(x.x,wsc4[p]); q.h[1]=(__bf16)qclamp(x.y,wsc4[p]);
          q.h[2]=(__bf16)qclamp(x.z,wsc4[p]); q.h[3]=(__bf16)qclamp(x.w,wsc4[p]);
          q.h[4]=(__bf16)qclamp(z.x,wsc4[p]); q.h[5]=(__bf16)qclamp(z.y,wsc4[p]);
          q.h[6]=(__bf16)qclamp(z.z,wsc4[p]); q.h[7]=(__bf16)qclamp(z.w,wsc4[p]);
        }
        *(bf16x8*)&Ws[r][sc] = q.v;
      }
    }
    __syncthreads();
    #pragma unroll
    for (int kk = 0; kk < 64; kk += 32) {
      bf16x8 af[4], bfr[4];
      #pragma unroll
      for (int i = 0; i < 4; i++) {
        af[i]  = *(const bf16x8*)&As[wm + i * 16 + l15][kk + quad * 8];
        bfr[i] = *(const bf16x8*)&Ws[wn + i * 16 + l15][kk + quad * 8];
      }
      #pragma unroll
      for (int i = 0; i < 4; i++)
        #pragma unroll
        for (int j = 0; j < 4; j++)
          acc[i][j] = __builtin_amdgcn_mfma_f32_16x16x32_bf16(af[i], bfr[j], acc[i][j], 0, 0, 0);
    }
  }
  float asc = slot_scale(aslot);
  #pragma unroll
  for (int j = 0; j < 4; j++) {
    int gn = n0 + wn + j * 16 + l15;
    float wsb = wrow[gn] * asc;
    float bv = ldin(a.bias[mat], gn, bf);
    #pragma unroll
    for (int i = 0; i < 4; i++)
      #pragma unroll
      for (int r = 0; r < 4; r++) {
        int gm = wm + i * 16 + quad * 4 + r;    // C/D: col=lane&15, row=quad*4+reg (m89)
        float val = acc[i][j][r] * wsb + bv;
        if (MODE == 0) {
          a.outs[blockIdx.z][(size_t)(gn >> 7) * (SEQ * DH) + (size_t)(outrow + gm) * DH + (gn & 127)] = val;
        } else {
          size_t idx = (size_t)(outrow + gm) * DM + gn;
          if (bf) ((__bf16*)a.dout)[idx] = (__bf16)val; else ((float*)a.dout)[idx] = val;
        }
      }
  }
}

// ===== Flash attention: Br=64 (4 waves x 16 rows), Bc=32 =====
// Round-12: global_load_lds DMA staging (T3 2-phase). Rounds 2-6 proved the
// global->VGPR->LDS staging path spills scratch under EVERY launch-bounds
// setting (R6: even uncapped, 260 MB scratch, VGPR 72) -- the allocator
// pipelines the staging loads across barrier regions and spills rather than
// de-pipeline. Fix: remove the staging registers entirely via
// __builtin_amdgcn_global_load_lds (width 16), LDS double-buffer, ONE
// __syncthreads per tile. DMAs for tile kt+1 are issued BEFORE tile kt's
// compute; the NEXT iteration's __syncthreads (vmcnt(0)+barrier) drains them
// after compute has hidden the HBM latency. Zero staging regs -> no spill.
// global_load_lds needs LINEAR LDS (no padding, m104), so bank conflicts are
// fixed with both-sides XOR swizzles (rule #21): inverse-swizzled GLOBAL
// source + swizzled ds_read, LDS linear.
//   K tile [32 s-rows][256 B]: byte ^= (row&7)<<4   (read: 2-way, free)
//   V tile [128 d-rows][64 B]: byte ^= ((row>>1)&3)<<4 (read: exactly 2-way)
// Ps stays padded+ds_write (wave-private rows, no barrier).
// LDS: K dbuf 16K + V dbuf 16K + Ps 5K = 37888 -> 4 blocks/CU; regs ~95
// uncapped -> 4 waves/SIMD from both limits.
template<int SPLIT>
__global__ __launch_bounds__(256)
void flash_attn_k(const __bf16* __restrict__ Qb, const __bf16* __restrict__ Kb,
                  const __bf16* __restrict__ Vt, float* __restrict__ O,
                  float* __restrict__ Op, float* __restrict__ Mp, float* __restrict__ Lp) {
  __shared__ __align__(16) char smem[8192 * 4 + 5120];
  // layout: K0 | K1 | V0 | V1 | Ps
  const int t = threadIdx.x, lane = t & 63, wave = t >> 6;
  const int l15 = lane & 15, quad = lane >> 4;
  const int h = blockIdx.y, s0 = blockIdx.x * 64, qr = wave * 16;
  const float fscale = 0.08838834764831845f * 1.4426950408889634f;  // sm_scale*log2e

  bf16x8 qf[4];
  #pragma unroll
  for (int kk = 0; kk < 4; kk++)
    qf[kk] = *(const bf16x8*)&Qb[(size_t)(h * SEQ + s0 + qr + l15) * DH + kk * 32 + quad * 8];

  f32x4 accO[8] = {};
  float m_st[4], l_st[4];
  #pragma unroll
  for (int r = 0; r < 4; r++) { m_st[r] = -1e30f; l_st[r] = 0.f; }

  const int NT = SEQ / 32;                       // 72 tiles
  const int ktb = SPLIT ? blockIdx.z * (NT / NSPLIT) : 0;
  const int kte = SPLIT ? ktb + (NT / NSPLIT) : NT;

  // --- DMA staging geometry (per thread, loop-invariant) ---
  // chunk id c = wave*2 + j  (8 chunks of 1024 B each for K and for V)
  // K: o = c*1024 + lane*16; row = o>>8 in [0,32); C' = o&255; src col = C'^((row&7)<<4)
  // V: o = c*1024 + lane*16; row = o>>6 in [0,128); C' = o&63; src col = C'^(((row>>1)&3)<<4)
  int ldso[2], kgo[2], vgo[2];
  #pragma unroll
  for (int j = 0; j < 2; j++) {
    int o = (wave * 2 + j) * 1024 + lane * 16;
    ldso[j] = o;
    int krow = o >> 8, kcp = o & 255;
    kgo[j] = krow * 256 + (kcp ^ ((krow & 7) << 4));
    int vrow = o >> 6, vcp = o & 63;
    vgo[j] = vrow * (SEQ * 2) + (vcp ^ (((vrow >> 1) & 3) << 4));
  }
  const char* kgb = (const char*)Kb + (size_t)h * SEQ * (DH * 2);   // + kt*8192 + kgo
  const char* vgb = (const char*)Vt + (size_t)h * DH * (SEQ * 2);   // + kt*64 + vgo
  const int kmask = (l15 & 7) << 4;            // QK read swizzle (row&7 == l15&7)
  const int vmask = ((l15 >> 1) & 3) << 4;     // PV read swizzle ((row>>1)&3 == (l15>>1)&3)
  __bf16* PsB = (__bf16*)(smem + 32768);       // [64][40] bf16, stride 80 B

  auto stage = [&](int buf, int kt) {
    const char* ks = kgb + (size_t)kt * 8192;
    char* kd = smem + buf * 8192;
    #pragma unroll
    for (int j = 0; j < 2; j++)
      gload_lds16(ks + kgo[j], kd + ldso[j]);
    const char* vs = vgb + (size_t)kt * 64;
    char* vd = smem + 16384 + buf * 8192;
    #pragma unroll
    for (int j = 0; j < 2; j++)
      gload_lds16(vs + vgo[j], vd + ldso[j]);
  };

  int cur = 0;
  stage(0, ktb);
  for (int kt = ktb; kt < kte; kt++) {
    // vmcnt(0)+lgkmcnt(0)+barrier: buf[cur] DMAs (issued last iter, in flight
    // through all of last iter's compute) complete; all waves' reads of the
    // other buffer are done, so this iter's stage may overwrite it.
    __syncthreads();
    if (kt + 1 < kte) stage(cur ^ 1, kt + 1);

    const char* Kc = smem + cur * 8192;
    const char* Vc = smem + 16384 + cur * 8192;

    f32x4 accS[2] = {};
    __builtin_amdgcn_s_setprio(1);
    #pragma unroll
    for (int kk = 0; kk < 4; kk++)
      #pragma unroll
      for (int ni = 0; ni < 2; ni++) {
        bf16x8 bk = *(const bf16x8*)(Kc + (ni * 16 + l15) * 256 + ((kk * 64 + quad * 16) ^ kmask));
        accS[ni] = __builtin_amdgcn_mfma_f32_16x16x32_bf16(qf[kk], bk, accS[ni], 0, 0, 0);
      }
    __builtin_amdgcn_s_setprio(0);

    // Fused softmax per output row r: rowmax -> alpha -> exp/sum -> rescale accO.
    #pragma unroll
    for (int r = 0; r < 4; r++) {
      float rm = fmaxf(accS[0][r], accS[1][r]);
      #pragma unroll
      for (int off = 8; off > 0; off >>= 1) rm = fmaxf(rm, __shfl_xor(rm, off));
      float mn = fmaxf(m_st[r], rm);
      float al = exp2f((m_st[r] - mn) * fscale);
      m_st[r] = mn;
      float rs = 0.f;
      #pragma unroll
      for (int ni = 0; ni < 2; ni++) {
        float pv = exp2f((accS[ni][r] - mn) * fscale);
        accS[ni][r] = pv;
        rs += pv;
      }
      #pragma unroll
      for (int off = 8; off > 0; off >>= 1) rs += __shfl_xor(rs, off);
      l_st[r] = l_st[r] * al + rs;
      #pragma unroll
      for (int di = 0; di < 8; di++)
        accO[di][r] *= al;
    }
    // Ps rows [qr, qr+16) are wave-private (no barrier needed).
    #pragma unroll
    for (int ni = 0; ni < 2; ni++)
      #pragma unroll
      for (int r = 0; r < 4; r++)
        PsB[(qr + quad * 4 + r) * 40 + ni * 16 + l15] = (__bf16)accS[ni][r];
    // PV (K=32, single k-step): Ps same-wave RAW via compiler lgkmcnt; Vs stable.
    __builtin_amdgcn_s_setprio(1);
    {
      bf16x8 pa = *(const bf16x8*)((const char*)PsB + (qr + l15) * 80 + quad * 16);
      #pragma unroll
      for (int di = 0; di < 8; di++) {
        bf16x8 vb = *(const bf16x8*)(Vc + (di * 16 + l15) * 64 + ((quad * 16) ^ vmask));
        accO[di] = __builtin_amdgcn_mfma_f32_16x16x32_bf16(pa, vb, accO[di], 0, 0, 0);
      }
    }
    __builtin_amdgcn_s_setprio(0);
    cur ^= 1;
  }
  if (SPLIT) {
    const size_t SP = (size_t)NH * SEQ * DH;
    const int sp = blockIdx.z;
    #pragma unroll
    for (int r = 0; r < 4; r++) {
      int gs = s0 + qr + quad * 4 + r;
      size_t ib = sp * SP + ((size_t)h * SEQ + gs) * DH;
      if (l15 == 0) {
        Mp[(size_t)sp * NH * SEQ + h * SEQ + gs] = m_st[r];
        Lp[(size_t)sp * NH * SEQ + h * SEQ + gs] = l_st[r];
      }
      #pragma unroll
      for (int di = 0; di < 8; di++)
        Op[ib + di * 16 + l15] = accO[di][r];
    }
  } else {
    #pragma unroll
    for (int r = 0; r < 4; r++) {
      float inv = 1.0f / l_st[r];
      int gs = s0 + qr + quad * 4 + r;
      #pragma unroll
      for (int di = 0; di < 8; di++)
        O[(size_t)gs * DM + h * DH + di * 16 + l15] = accO[di][r] * inv;
    }
  }
}

// Merge NSPLIT partials + global absmax of result (feeds attn-out quant).
__global__ void flash_combine_k(const float* __restrict__ Op, const float* __restrict__ Mp,
                                const float* __restrict__ Lp, float* __restrict__ O,
                                unsigned* __restrict__ slot8) {
  const float fscale = 0.08838834764831845f * 1.4426950408889634f;
  const int t = threadIdx.x, lane = t & 63, w = t >> 6;   // 1024 thr, 16 waves
  const size_t SP = (size_t)NH * SEQ * DH, MR = (size_t)NH * SEQ;
  float lm = 0.f;
  for (int row = blockIdx.x * 16 + w; row < NH * SEQ; row += gridDim.x * 16) {
    float m0 = Mp[row], m1 = Mp[MR + row], m2 = Mp[2 * MR + row], m3 = Mp[3 * MR + row];
    float M = fmaxf(fmaxf(m0, m1), fmaxf(m2, m3));
    float w0 = exp2f((m0 - M) * fscale), w1 = exp2f((m1 - M) * fscale);
    float w2 = exp2f((m2 - M) * fscale), w3 = exp2f((m3 - M) * fscale);
    float inv = 1.0f / (Lp[row] * w0 + Lp[MR + row] * w1 + Lp[2 * MR + row] * w2 + Lp[3 * MR + row] * w3);
    int h = row / SEQ, s = row % SEQ;
    size_t ob = (size_t)s * DM + h * DH, ib = (size_t)row * DH;
    #pragma unroll
    for (int j = 0; j < 2; j++) {
      int d = lane + j * 64;
      float v = (Op[ib + d] * w0 + Op[SP + ib + d] * w1 +
                 Op[2 * SP + ib + d] * w2 + Op[3 * SP + ib + d] * w3) * inv;
      O[ob + d] = v;
      lm = fmaxf(lm, fabsf(v));
    }
  }
  lm = block_allmax_n(lm);
  if (t == 0) atomicMax(slot8, __float_as_uint(lm));
}

extern "C" void kernel_launch(void* const* d_in, const int* in_sizes, int n_in,
                              void* d_out, int out_size, void* d_ws, size_t ws_size,
                              hipStream_t stream) {
  (void)in_sizes; (void)n_in; (void)out_size;
  const void* hs   = d_in[0];
  const void* es   = d_in[1];
  const void* cosb = d_in[2];
  const void* sinb = d_in[3];
  const void* W[8]; const void* Bv[8];
  for (int i = 0; i < 8; i++) { W[i] = d_in[4 + 2 * i]; Bv[i] = d_in[5 + 2 * i]; }
  const void* nq  = d_in[20];
  const void* nk  = d_in[21];
  const void* naq = d_in[22];
  const void* nak = d_in[23];

  char* ws = (char*)d_ws;
  size_t off = 0;
  auto take = [&](size_t b) { char* p = ws + off; off += (b + 255) & ~(size_t)255; return p; };
  const size_t T = (size_t)NH * SEQ * DH * 4;      // 18.87 MB (one fp32 qkv tensor)

  unsigned* slots = (unsigned*)take(16 * SSTR * 4);   // 9 scale slots + flag, 128 B apart
  int* flagp = (int*)(slots + 15 * SSTR);
  float* wsc = (float*)take(8ull * DM * 4);

  size_t here = off;
  size_t need_base  = 4 * T + T + 3 * (T / 2) + 2 * ((size_t)NSPLIT * NH * SEQ * 4 + 256) + 1024;
  bool do_split = here + need_base <= ws_size;
  size_t region_sz = do_split ? 4 * T : 3 * T;

  char* region = take(region_sz);                  // qf,kf,vf; later Opart(+attnq)
  float* qf = (float*)region;
  float* kf = (float*)(region + T);
  float* vf = (float*)(region + 2 * T);
  float* Opart = (float*)region;
  __bf16* attnq = (__bf16*)region;                 // after combine (Opart dead)
  char* attnfR = take(T);                          // hq+eq early; attnf after flash
  __bf16* hq = (__bf16*)attnfR;
  __bf16* eq = (__bf16*)(attnfR + (size_t)L_IMG * DM * 2);
  float* attnf = (float*)attnfR;
  __bf16* qb  = (__bf16*)take(T / 2);
  __bf16* kb  = (__bf16*)take(T / 2);
  __bf16* vtb = (__bf16*)take(T / 2);
  float* Mpart = (float*)take((size_t)NSPLIT * NH * SEQ * 4);
  float* Lpart = (float*)take((size_t)NSPLIT * NH * SEQ * 4);
  bool do_prequant = (off + 8ull * DM * DM * 2 + 256 <= ws_size);
  __bf16* wq = do_prequant ? (__bf16*)take(8ull * DM * DM * 2) : nullptr;

  hipMemsetAsync(slots, 0, 16 * SSTR * 4, stream);
  detect_k<<<1, 64, 0, stream>>>(cosb, flagp);

  Ptrs8 win;
  for (int i = 0; i < 8; i++) win.p[i] = W[i];
  if (do_prequant)
    quant_weights_k<<<dim3(DM, 8), 256, 0, stream>>>(win, wq, wsc, flagp);
  else
    weight_scales_k<<<dim3(DM, 8), 256, 0, stream>>>(win, wsc, flagp);

  absmax_he_k<<<512, 256, 0, stream>>>(hs, es, slots, slots + SSTR, flagp);
  quant_he_k<<<1024, 256, 0, stream>>>(hs, es, slots, hq, eq, flagp);

  GemmArgs ga;
  ga.hq = hq; ga.eq = eq; ga.attnq = attnq; ga.wqp = wq;
  for (int i = 0; i < 8; i++) { ga.Wraw[i] = W[i]; ga.bias[i] = Bv[i]; }
  ga.wsc = wsc; ga.outs[0] = qf; ga.outs[1] = kf; ga.outs[2] = vf;
  ga.dout = d_out; ga.slots = slots; ga.flagp = flagp;

  if (do_prequant)
    gemm_f<0, 1><<<dim3(16, 18, 3), 256, 0, stream>>>(ga);
  else
    gemm_f<0, 0><<<dim3(16, 18, 3), 256, 0, stream>>>(ga);

  rms_absmax_v_k<<<256, 1024, 0, stream>>>(qf, kf, vf, nq, naq, nk, nak, slots, flagp);
  rope2_k<<<1024, 256, 0, stream>>>(qf, kf, cosb, sinb, slots, qb, kb, flagp);
  quant_transpose_v_k<<<dim3(SEQ / 64, DH / 64, NH), 256, 0, stream>>>(vf, slots, vtb);

  if (do_split) {
    flash_attn_k<1><<<dim3(SEQ / 64, NH, NSPLIT), 256, 0, stream>>>(qb, kb, vtb, nullptr,
                                                                    Opart, Mpart, Lpart);
    flash_combine_k<<<288, 1024, 0, stream>>>(Opart, Mpart, Lpart, attnf, slots + 8 * SSTR);
  } else {
    flash_attn_k<0><<<dim3(SEQ / 64, NH), 256, 0, stream>>>(qb, kb, vtb, attnf,
                                                            nullptr, nullptr, nullptr);
    absmax_f32_k<<<256, 256, 0, stream>>>(attnf, SEQ * DM, slots + 8 * SSTR);
  }
  quant_f32x8_k<<<1024, 256, 0, stream>>>(attnf, SEQ * DM / 8, slots + 8 * SSTR, attnq);

  if (do_prequant)
    gemm_f<1, 1><<<dim3(16, 18), 256, 0, stream>>>(ga);
  else
    gemm_f<1, 0><<<dim3(16, 18), 256, 0, stream>>>(ga);
}

// Round 8
// 623.895 us; speedup vs baseline: 1.1989x; 1.0466x over previous
//
#include <hip/hip_runtime.h>

// ===== Problem constants =====
constexpr int L_TXT = 256, L_IMG = 2048, SEQ = 2304;
constexpr int DM = 2048, NH = 16, DH = 128;
constexpr int NSPLIT = 4;      // flash split-K factor
constexpr int SSTR = 32;       // slot stride in unsigneds (128 B) - avoids atomic cacheline ping-pong

typedef __attribute__((ext_vector_type(8))) __bf16 bf16x8;
typedef __attribute__((ext_vector_type(4))) float f32x4;

// Runtime dtype flag: 0 = fp32 storage, 1 = bf16 (detected from rope_cos[0]).
__device__ __forceinline__ float ldin(const void* p, size_t i, int bf) {
  return bf ? (float)((const __bf16*)p)[i] : ((const float*)p)[i];
}
__device__ __forceinline__ float slot_scale(const unsigned* s) {
  return fmaxf(__uint_as_float(*s) / 127.0f, 1e-8f);
}
__device__ __forceinline__ float qclamp(float x, float sc) {
  float q = rintf(x / sc);     // RNE, matches jnp.round
  return fminf(fmaxf(q, -127.0f), 127.0f);
}
// Direct global->LDS DMA, 16 B per lane. LDS dest = wave-uniform base + lane*16.
__device__ __forceinline__ void gload_lds16(const void* g, void* l) {
  __builtin_amdgcn_global_load_lds(
      (const __attribute__((address_space(1))) unsigned int*)g,
      (__attribute__((address_space(3))) unsigned int*)l, 16, 0, 0);
}
__device__ __forceinline__ float block_allmax_n(float v) {  // any blockDim multiple of 64 (<=1024)
  #pragma unroll
  for (int off = 32; off; off >>= 1) v = fmaxf(v, __shfl_xor(v, off));
  __shared__ float sm[16];
  int nw = blockDim.x >> 6;
  __syncthreads();
  if ((threadIdx.x & 63) == 0) sm[threadIdx.x >> 6] = v;
  __syncthreads();
  float m = sm[0];
  for (int i = 1; i < nw; i++) m = fmaxf(m, sm[i]);
  return m;
}

__global__ void detect_k(const void* cosp, int* flag) {
  if (threadIdx.x == 0) *flag = (((const unsigned short*)cosp)[0] != 0) ? 1 : 0;
}

struct Ptrs8 { const void* p[8]; };

// ===== Weight quantization (vectorized): scales + int-grid bf16 weights =====
__global__ void quant_weights_k(Ptrs8 win, __bf16* __restrict__ wq, float* __restrict__ scales,
                                const int* __restrict__ flagp) {
  const int bf = *flagp;
  int row = blockIdx.x, mat = blockIdx.y, t = threadIdx.x;
  float v[8];
  if (bf) {
    union { int4 q; __bf16 h[8]; } u;
    u.q = ((const int4*)((const __bf16*)win.p[mat] + (size_t)row * DM))[t];
    #pragma unroll
    for (int j = 0; j < 8; j++) v[j] = (float)u.h[j];
  } else {
    const float4* p = (const float4*)((const float*)win.p[mat] + (size_t)row * DM);
    float4 a = p[t * 2], b = p[t * 2 + 1];
    v[0]=a.x; v[1]=a.y; v[2]=a.z; v[3]=a.w; v[4]=b.x; v[5]=b.y; v[6]=b.z; v[7]=b.w;
  }
  float m = 0.f;
  #pragma unroll
  for (int j = 0; j < 8; j++) m = fmaxf(m, fabsf(v[j]));
  m = block_allmax_n(m);
  float sc = fmaxf(m / 127.0f, 1e-8f);
  if (t == 0) scales[mat * DM + row] = sc;
  union { int4 q; __bf16 h[8]; } o;
  #pragma unroll
  for (int j = 0; j < 8; j++) o.h[j] = (__bf16)qclamp(v[j], sc);
  ((int4*)(wq + (size_t)mat * DM * DM + (size_t)row * DM))[t] = o.q;
}
// fallback: scales only
__global__ void weight_scales_k(Ptrs8 win, float* __restrict__ scales, const int* __restrict__ flagp) {
  const int bf = *flagp;
  int row = blockIdx.x, mat = blockIdx.y, t = threadIdx.x;
  float m = 0.f;
  for (int c = t; c < DM; c += 256) m = fmaxf(m, fabsf(ldin(win.p[mat], (size_t)row * DM + c, bf)));
  m = block_allmax_n(m);
  if (t == 0) scales[mat * DM + row] = fmaxf(m / 127.0f, 1e-8f);
}

// ===== absmax of hidden + encoder in one pass (vectorized x8) =====
__global__ void absmax_he_k(const void* __restrict__ hs, const void* __restrict__ es,
                            unsigned* s0, unsigned* s1, const int* __restrict__ flagp) {
  const int bf = *flagp;
  const int n18 = L_IMG * DM / 8, n28 = L_TXT * DM / 8;
  float m1 = 0.f, m2 = 0.f;
  for (int i = blockIdx.x * 256 + threadIdx.x; i < n18 + n28; i += gridDim.x * 256) {
    bool h = i < n18;
    const void* src = h ? hs : es;
    int j = h ? i : i - n18;
    float lm = 0.f;
    if (bf) {
      union { int4 q; __bf16 x[8]; } u; u.q = ((const int4*)src)[j];
      #pragma unroll
      for (int k = 0; k < 8; k++) lm = fmaxf(lm, fabsf((float)u.x[k]));
    } else {
      const float4* p = (const float4*)src;
      float4 a = p[j * 2], b = p[j * 2 + 1];
      lm = fmaxf(fmaxf(fmaxf(fabsf(a.x), fabsf(a.y)), fmaxf(fabsf(a.z), fabsf(a.w))),
                 fmaxf(fmaxf(fabsf(b.x), fabsf(b.y)), fmaxf(fabsf(b.z), fabsf(b.w))));
    }
    if (h) m1 = fmaxf(m1, lm); else m2 = fmaxf(m2, lm);
  }
  m1 = block_allmax_n(m1);
  __syncthreads();
  m2 = block_allmax_n(m2);
  if (threadIdx.x == 0) { atomicMax(s0, __float_as_uint(m1)); atomicMax(s1, __float_as_uint(m2)); }
}

// ===== quantize hidden+encoder to int-grid bf16 (vectorized x8) =====
__global__ void quant_he_k(const void* __restrict__ hs, const void* __restrict__ es,
                           const unsigned* __restrict__ slots, __bf16* __restrict__ hqo,
                           __bf16* __restrict__ eqo, const int* __restrict__ flagp) {
  const int bf = *flagp;
  const int n18 = L_IMG * DM / 8, n28 = L_TXT * DM / 8;
  float sc0 = slot_scale(slots), sc1 = slot_scale(slots + SSTR);
  for (int i = blockIdx.x * 256 + threadIdx.x; i < n18 + n28; i += gridDim.x * 256) {
    bool h = i < n18;
    const void* src = h ? hs : es;
    int j = h ? i : i - n18;
    float sc = h ? sc0 : sc1;
    float v[8];
    if (bf) {
      union { int4 q; __bf16 x[8]; } u; u.q = ((const int4*)src)[j];
      #pragma unroll
      for (int k = 0; k < 8; k++) v[k] = (float)u.x[k];
    } else {
      const float4* p = (const float4*)src;
      float4 a = p[j * 2], b = p[j * 2 + 1];
      v[0]=a.x; v[1]=a.y; v[2]=a.z; v[3]=a.w; v[4]=b.x; v[5]=b.y; v[6]=b.z; v[7]=b.w;
    }
    union { int4 q; __bf16 x[8]; } o;
    #pragma unroll
    for (int k = 0; k < 8; k++) o.x[k] = (__bf16)qclamp(v[k], sc);
    ((int4*)(h ? hqo : eqo))[j] = o.q;
  }
}

// ===== quantize fp32 attn-out to int-grid bf16 (vectorized x8) =====
__global__ void quant_f32x8_k(const float* __restrict__ x, int n8,
                              const unsigned* __restrict__ slot, __bf16* __restrict__ out) {
  float sc = slot_scale(slot);
  for (int i = blockIdx.x * 256 + threadIdx.x; i < n8; i += gridDim.x * 256) {
    float4 a = ((const float4*)x)[i * 2], b = ((const float4*)x)[i * 2 + 1];
    union { int4 q; __bf16 h[8]; } o;
    o.h[0]=(__bf16)qclamp(a.x,sc); o.h[1]=(__bf16)qclamp(a.y,sc);
    o.h[2]=(__bf16)qclamp(a.z,sc); o.h[3]=(__bf16)qclamp(a.w,sc);
    o.h[4]=(__bf16)qclamp(b.x,sc); o.h[5]=(__bf16)qclamp(b.y,sc);
    o.h[6]=(__bf16)qclamp(b.z,sc); o.h[7]=(__bf16)qclamp(b.w,sc);
    ((int4*)out)[i] = o.q;
  }
}
// fallback absmax (non-split flash path)
__global__ void absmax_f32_k(const float* __restrict__ x, int n, unsigned* slot) {
  float m = 0.f;
  for (int i = blockIdx.x * 256 + threadIdx.x; i < n; i += gridDim.x * 256)
    m = fmaxf(m, fabsf(x[i]));
  m = block_allmax_n(m);
  if (threadIdx.x == 0) atomicMax(slot, __float_as_uint(m));
}

// ===== fused: rmsnorm(q)+absmax, rmsnorm(k)+absmax, absmax(v) =====
__global__ void rms_absmax_v_k(float* __restrict__ qf, float* __restrict__ kf, float* __restrict__ vf,
                               const void* nq, const void* naq, const void* nk, const void* nak,
                               unsigned* __restrict__ slots, const int* __restrict__ flagp) {
  const int bf = *flagp;
  const int t = threadIdx.x, lane = t & 63, wave = t >> 6;   // 1024 thr = 16 waves
  float wqt0 = ldin(naq, lane, bf), wqt1 = ldin(naq, lane + 64, bf);
  float wqi0 = ldin(nq,  lane, bf), wqi1 = ldin(nq,  lane + 64, bf);
  float wkt0 = ldin(nak, lane, bf), wkt1 = ldin(nak, lane + 64, bf);
  float wki0 = ldin(nk,  lane, bf), wki1 = ldin(nk,  lane + 64, bf);
  const int NR = NH * SEQ;
  float mx[6] = {0.f, 0.f, 0.f, 0.f, 0.f, 0.f};
  for (int row = blockIdx.x * 16 + wave; row < 3 * NR; row += gridDim.x * 16) {
    int tns = row / NR, r2 = row - tns * NR;
    int s = r2 % SEQ; bool txt = s < L_TXT;
    float* p = (tns == 0 ? qf : tns == 1 ? kf : vf) + (size_t)r2 * DH;
    float v0 = p[lane], v1 = p[lane + 64];
    if (tns < 2) {
      float ss = v0 * v0 + v1 * v1;
      #pragma unroll
      for (int off = 32; off; off >>= 1) ss += __shfl_xor(ss, off);
      float r = rsqrtf(ss * (1.0f / 128.0f) + 1e-6f);
      float w0, w1;
      if (tns == 0) { w0 = txt ? wqt0 : wqi0; w1 = txt ? wqt1 : wqi1; }
      else          { w0 = txt ? wkt0 : wki0; w1 = txt ? wkt1 : wki1; }
      v0 *= r * w0; v1 *= r * w1;
      p[lane] = v0; p[lane + 64] = v1;
    }
    int idx = tns * 2 + (txt ? 0 : 1);
    mx[idx] = fmaxf(mx[idx], fmaxf(fabsf(v0), fabsf(v1)));
  }
  #pragma unroll
  for (int off = 32; off; off >>= 1)
    #pragma unroll
    for (int j = 0; j < 6; j++) mx[j] = fmaxf(mx[j], __shfl_xor(mx[j], off));
  __shared__ float smx[16][6];
  if (lane == 0)
    #pragma unroll
    for (int j = 0; j < 6; j++) smx[wave][j] = mx[j];
  __syncthreads();
  if (t == 0) {
    #pragma unroll
    for (int j = 0; j < 6; j++) {
      float m = smx[0][j];
      for (int i = 1; i < 16; i++) m = fmaxf(m, smx[i][j]);
      atomicMax(slots + (2 + j) * SSTR, __float_as_uint(m));
    }
  }
}

// ===== fused rope for q and k: quantize (dequant) + rotate + bf16 =====
__global__ void rope2_k(const float* __restrict__ qf, const float* __restrict__ kf,
                        const void* cosb, const void* sinb, const unsigned* __restrict__ slots,
                        __bf16* __restrict__ qb, __bf16* __restrict__ kb, const int* __restrict__ flagp) {
  const int bf = *flagp;
  const int NP = NH * SEQ * 64;
  for (int i = blockIdx.x * 256 + threadIdx.x; i < 2 * NP; i += gridDim.x * 256) {
    int tns = i >= NP;
    int j = i - tns * NP;
    int pr = j & 63, rowg = j >> 6;
    int s = rowg % SEQ;
    const float* src = tns ? kf : qf;
    __bf16* dst = tns ? kb : qb;
    float sc = slot_scale(slots + (tns ? 4 : 2) * SSTR + (s < L_TXT ? 0 : SSTR));
    size_t base = (size_t)rowg * DH + pr * 2;
    float2 x2 = *(const float2*)(src + base);
    float q0 = qclamp(x2.x, sc) * sc, q1 = qclamp(x2.y, sc) * sc;
    float c0 = ldin(cosb, s * DH + 2 * pr, bf), c1 = ldin(cosb, s * DH + 2 * pr + 1, bf);
    float s0 = ldin(sinb, s * DH + 2 * pr, bf), s1 = ldin(sinb, s * DH + 2 * pr + 1, bf);
    dst[base]     = (__bf16)(q0 * c0 - q1 * s0);
    dst[base + 1] = (__bf16)(q1 * c1 + q0 * s1);
  }
}

// ===== V: quantize + transpose [NH][SEQ][DH] -> [NH][DH][SEQ] =====
__global__ void quant_transpose_v_k(const float* __restrict__ v, const unsigned* __restrict__ slots,
                                    __bf16* __restrict__ vt) {
  __shared__ float tile[64][65];
  int t = threadIdx.x;
  int s0 = blockIdx.x * 64, d0 = blockIdx.y * 64, h = blockIdx.z;
  #pragma unroll
  for (int i = 0; i < 16; i++) {
    int r = i * 4 + (t >> 6), c = t & 63;
    tile[r][c] = v[((size_t)(h * SEQ) + s0 + r) * DH + d0 + c];
  }
  __syncthreads();
  float sc = slot_scale(slots + (s0 < L_TXT ? 6 : 7) * SSTR);
  #pragma unroll
  for (int i = 0; i < 16; i++) {
    int d = i * 4 + (t >> 6), s = t & 63;
    float q = qclamp(tile[s][d], sc) * sc;
    vt[((size_t)(h * DH) + d0 + d) * SEQ + s0 + s] = (__bf16)q;
  }
}

// ===== GEMM (fused launches) =====
struct GemmArgs {
  const __bf16 *hq, *eq, *attnq;
  const __bf16* wqp;
  const void* Wraw[8];
  const float* wsc;
  const void* bias[8];
  float* outs[3];
  void* dout;
  const unsigned* slots;
  const int* flagp;
};
template<int MODE, int QW>
__global__ __launch_bounds__(256, 2)
void gemm_f(GemmArgs a) {
  const int bf = *a.flagp;
  constexpr int K = DM;
  __shared__ __bf16 As[128][72];
  __shared__ __bf16 Ws[128][72];
  const int t = threadIdx.x, lane = t & 63, wave = t >> 6;
  const int l15 = lane & 15, quad = lane >> 4;
  const int n0 = blockIdx.x * 128, y = blockIdx.y;
  int mat, outrow; const __bf16* A; const unsigned* aslot;
  if (MODE == 0) {
    bool txt = y < 2;
    mat = blockIdx.z + (txt ? 3 : 0);
    A = (txt ? a.eq : a.hq) + (size_t)(txt ? y * 128 : (y - 2) * 128) * K;
    outrow = y * 128;
    aslot = a.slots + (txt ? SSTR : 0);
  } else {
    bool img = y < 16;
    mat = img ? 6 : 7;
    A = a.attnq + (size_t)(img ? L_TXT + y * 128 : (y - 16) * 128) * K;
    outrow = img ? y * 128 : L_IMG + (y - 16) * 128;
    aslot = a.slots + 8 * SSTR;
  }
  const __bf16* Wq = QW ? a.wqp + (size_t)mat * DM * DM : nullptr;
  const void* Wr = a.Wraw[mat];
  const float* wrow = a.wsc + mat * DM;
  int wm = (wave & 1) * 64, wn = (wave >> 1) * 64;
  f32x4 acc[4][4] = {};
  int sr = t >> 3, sc = (t & 7) * 8;
  float wsc4[4];
  if (!QW) {
    #pragma unroll
    for (int p = 0; p < 4; p++) wsc4[p] = wrow[n0 + p * 32 + sr];
  }
  for (int k0 = 0; k0 < K; k0 += 64) {
    __syncthreads();
    #pragma unroll
    for (int p = 0; p < 4; p++) {
      int r = p * 32 + sr;
      *(int4*)&As[r][sc] = *(const int4*)&A[(size_t)r * K + k0 + sc];
      if (QW) {
        *(int4*)&Ws[r][sc] = *(const int4*)&Wq[(size_t)(n0 + r) * K + k0 + sc];
      } else {
        union { bf16x8 v; __bf16 h[8]; } q;
        if (bf) {
          union { int4 v; __bf16 h[8]; } u;
          u.v = *(const int4*)((const __bf16*)Wr + (size_t)(n0 + r) * K + k0 + sc);
          #pragma unroll
          for (int j = 0; j < 8; j++) q.h[j] = (__bf16)qclamp((float)u.h[j], wsc4[p]);
        } else {
          const float* wp = (const float*)Wr + (size_t)(n0 + r) * K + k0 + sc;
          float4 x = *(const float4*)wp, z = *(const float4*)(wp + 4);
          q.h[0]=(__bf16)qclamp(x.x,wsc4[p]); q.h[1]=(__bf16)qclamp(x.y,wsc4[p]);
          q.h[2]=(__bf16)qclamp(x.z,wsc4[p]); q.h[3]=(__bf16)qclamp(x.w,wsc4[p]);
          q.h[4]=(__bf16)qclamp(z.x,wsc4[p]); q.h[5]=(__bf16)qclamp(z.y,wsc4[p]);
          q.h[6]=(__bf16)qclamp(z.z,wsc4[p]); q.h[7]=(__bf16)qclamp(z.w,wsc4[p]);
        }
        *(bf16x8*)&Ws[r][sc] = q.v;
      }
    }
    __syncthreads();
    #pragma unroll
    for (int kk = 0; kk < 64; kk += 32) {
      bf16x8 af[4], bfr[4];
      #pragma unroll
      for (int i = 0; i < 4; i++) {
        af[i]  = *(const bf16x8*)&As[wm + i * 16 + l15][kk + quad * 8];
        bfr[i] = *(const bf16x8*)&Ws[wn + i * 16 + l15][kk + quad * 8];
      }
      #pragma unroll
      for (int i = 0; i < 4; i++)
        #pragma unroll
        for (int j = 0; j < 4; j++)
          acc[i][j] = __builtin_amdgcn_mfma_f32_16x16x32_bf16(af[i], bfr[j], acc[i][j], 0, 0, 0);
    }
  }
  float asc = slot_scale(aslot);
  #pragma unroll
  for (int j = 0; j < 4; j++) {
    int gn = n0 + wn + j * 16 + l15;
    float wsb = wrow[gn] * asc;
    float bv = ldin(a.bias[mat], gn, bf);
    #pragma unroll
    for (int i = 0; i < 4; i++)
      #pragma unroll
      for (int r = 0; r < 4; r++) {
        int gm = wm + i * 16 + quad * 4 + r;    // C/D: col=lane&15, row=quad*4+reg (m89)
        float val = acc[i][j][r] * wsb + bv;
        if (MODE == 0) {
          a.outs[blockIdx.z][(size_t)(gn >> 7) * (SEQ * DH) + (size_t)(outrow + gm) * DH + (gn & 127)] = val;
        } else {
          size_t idx = (size_t)(outrow + gm) * DM + gn;
          if (bf) ((__bf16*)a.dout)[idx] = (__bf16)val; else ((float*)a.dout)[idx] = val;
        }
      }
  }
}

// ===== Flash attention: Br=64 (4 waves x 16 rows), Bc=32 =====
// Round-13: defer-max (T13) + lazy-l on top of round-12's DMA staging.
// R12 post-mortem: spill eliminated (WRITE 352->75 MB = program writes), flash
// 228->160 us; profile flipped to VALU-bound (VALUBusy 55%, MfmaUtil 11.5%,
// HBM 13%). ~2370 cy/wave-tile vs ~100 cy MFMA: the per-tile softmax (~200
// VALU/DPP: 16 shfl-max, 16 shfl-add, 32 accO muls, 12 exp2, serial chains)
// is the consumer. This round:
//  - T13 defer-max THR=8: per-lane pmax check via __all (no reduce); common
//    case skips max-reduce + alpha + accO/l rescale entirely. P bounded by
//    2^(8*fscale)~2.0 (fine in bf16). First tile always triggers (m=-1e30),
//    so m stays 16-lane-uniform.
//  - lazy l: l_st[r] kept as per-lane partial (own 2 cols); cross-lane sum
//    ONCE at the end instead of per-tile. Rescale applies linearly: exact.
// Common-case softmax: ~25 ops/tile (4 fmax + cmp + 8 exp2 + 8 add).
// Staging/swizzles/1-barrier/setprio unchanged from R12.
template<int SPLIT>
__global__ __launch_bounds__(256)
void flash_attn_k(const __bf16* __restrict__ Qb, const __bf16* __restrict__ Kb,
                  const __bf16* __restrict__ Vt, float* __restrict__ O,
                  float* __restrict__ Op, float* __restrict__ Mp, float* __restrict__ Lp) {
  __shared__ __align__(16) char smem[8192 * 4 + 5120];
  // layout: K0 | K1 | V0 | V1 | Ps
  const int t = threadIdx.x, lane = t & 63, wave = t >> 6;
  const int l15 = lane & 15, quad = lane >> 4;
  const int h = blockIdx.y, s0 = blockIdx.x * 64, qr = wave * 16;
  const float fscale = 0.08838834764831845f * 1.4426950408889634f;  // sm_scale*log2e
  const float THR = 8.0f;                        // defer-max threshold (score units)

  bf16x8 qf[4];
  #pragma unroll
  for (int kk = 0; kk < 4; kk++)
    qf[kk] = *(const bf16x8*)&Qb[(size_t)(h * SEQ + s0 + qr + l15) * DH + kk * 32 + quad * 8];

  f32x4 accO[8] = {};
  float m_st[4], l_st[4];
  #pragma unroll
  for (int r = 0; r < 4; r++) { m_st[r] = -1e30f; l_st[r] = 0.f; }

  const int NT = SEQ / 32;                       // 72 tiles
  const int ktb = SPLIT ? blockIdx.z * (NT / NSPLIT) : 0;
  const int kte = SPLIT ? ktb + (NT / NSPLIT) : NT;

  // --- DMA staging geometry (per thread, loop-invariant) ---
  int ldso[2], kgo[2], vgo[2];
  #pragma unroll
  for (int j = 0; j < 2; j++) {
    int o = (wave * 2 + j) * 1024 + lane * 16;
    ldso[j] = o;
    int krow = o >> 8, kcp = o & 255;
    kgo[j] = krow * 256 + (kcp ^ ((krow & 7) << 4));
    int vrow = o >> 6, vcp = o & 63;
    vgo[j] = vrow * (SEQ * 2) + (vcp ^ (((vrow >> 1) & 3) << 4));
  }
  const char* kgb = (const char*)Kb + (size_t)h * SEQ * (DH * 2);   // + kt*8192 + kgo
  const char* vgb = (const char*)Vt + (size_t)h * DH * (SEQ * 2);   // + kt*64 + vgo
  const int kmask = (l15 & 7) << 4;            // QK read swizzle
  const int vmask = ((l15 >> 1) & 3) << 4;     // PV read swizzle
  __bf16* PsB = (__bf16*)(smem + 32768);       // [64][40] bf16, stride 80 B

  auto stage = [&](int buf, int kt) {
    const char* ks = kgb + (size_t)kt * 8192;
    char* kd = smem + buf * 8192;
    #pragma unroll
    for (int j = 0; j < 2; j++)
      gload_lds16(ks + kgo[j], kd + ldso[j]);
    const char* vs = vgb + (size_t)kt * 64;
    char* vd = smem + 16384 + buf * 8192;
    #pragma unroll
    for (int j = 0; j < 2; j++)
      gload_lds16(vs + vgo[j], vd + ldso[j]);
  };

  int cur = 0;
  stage(0, ktb);
  for (int kt = ktb; kt < kte; kt++) {
    // vmcnt(0)+lgkmcnt(0)+barrier: buf[cur] DMAs complete; other buffer free.
    __syncthreads();
    if (kt + 1 < kte) stage(cur ^ 1, kt + 1);

    const char* Kc = smem + cur * 8192;
    const char* Vc = smem + 16384 + cur * 8192;

    f32x4 accS[2] = {};
    __builtin_amdgcn_s_setprio(1);
    #pragma unroll
    for (int kk = 0; kk < 4; kk++)
      #pragma unroll
      for (int ni = 0; ni < 2; ni++) {
        bf16x8 bk = *(const bf16x8*)(Kc + (ni * 16 + l15) * 256 + ((kk * 64 + quad * 16) ^ kmask));
        accS[ni] = __builtin_amdgcn_mfma_f32_16x16x32_bf16(qf[kk], bk, accS[ni], 0, 0, 0);
      }
    __builtin_amdgcn_s_setprio(0);

    // T13 defer-max: per-lane pmax; skip reduce+rescale when no lane exceeds.
    float pmax[4], dmax = -1e30f;
    #pragma unroll
    for (int r = 0; r < 4; r++) {
      pmax[r] = fmaxf(accS[0][r], accS[1][r]);
      dmax = fmaxf(dmax, pmax[r] - m_st[r]);
    }
    if (!__all(dmax <= THR)) {
      #pragma unroll
      for (int r = 0; r < 4; r++) {
        float rm = pmax[r];
        #pragma unroll
        for (int off = 8; off > 0; off >>= 1) rm = fmaxf(rm, __shfl_xor(rm, off));
        float mn = fmaxf(m_st[r], rm);
        float al = exp2f((m_st[r] - mn) * fscale);
        m_st[r] = mn;
        l_st[r] *= al;
        #pragma unroll
        for (int di = 0; di < 8; di++)
          accO[di][r] *= al;
      }
    }
    // exp with (possibly stale) m; accumulate per-lane l partial (lazy-l).
    #pragma unroll
    for (int r = 0; r < 4; r++)
      #pragma unroll
      for (int ni = 0; ni < 2; ni++) {
        float pv = exp2f((accS[ni][r] - m_st[r]) * fscale);
        accS[ni][r] = pv;
        l_st[r] += pv;
      }
    // Ps rows [qr, qr+16) are wave-private (no barrier needed).
    #pragma unroll
    for (int ni = 0; ni < 2; ni++)
      #pragma unroll
      for (int r = 0; r < 4; r++)
        PsB[(qr + quad * 4 + r) * 40 + ni * 16 + l15] = (__bf16)accS[ni][r];
    // PV (K=32, single k-step): Ps same-wave RAW via compiler lgkmcnt; Vs stable.
    __builtin_amdgcn_s_setprio(1);
    {
      bf16x8 pa = *(const bf16x8*)((const char*)PsB + (qr + l15) * 80 + quad * 16);
      #pragma unroll
      for (int di = 0; di < 8; di++) {
        bf16x8 vb = *(const bf16x8*)(Vc + (di * 16 + l15) * 64 + ((quad * 16) ^ vmask));
        accO[di] = __builtin_amdgcn_mfma_f32_16x16x32_bf16(pa, vb, accO[di], 0, 0, 0);
      }
    }
    __builtin_amdgcn_s_setprio(0);
    cur ^= 1;
  }
  // lazy-l: one cross-lane sum at the end (was per-tile).
  #pragma unroll
  for (int r = 0; r < 4; r++)
    #pragma unroll
    for (int off = 8; off > 0; off >>= 1) l_st[r] += __shfl_xor(l_st[r], off);

  if (SPLIT) {
    const size_t SP = (size_t)NH * SEQ * DH;
    const int sp = blockIdx.z;
    #pragma unroll
    for (int r = 0; r < 4; r++) {
      int gs = s0 + qr + quad * 4 + r;
      size_t ib = sp * SP + ((size_t)h * SEQ + gs) * DH;
      if (l15 == 0) {
        Mp[(size_t)sp * NH * SEQ + h * SEQ + gs] = m_st[r];
        Lp[(size_t)sp * NH * SEQ + h * SEQ + gs] = l_st[r];
      }
      #pragma unroll
      for (int di = 0; di < 8; di++)
        Op[ib + di * 16 + l15] = accO[di][r];
    }
  } else {
    #pragma unroll
    for (int r = 0; r < 4; r++) {
      float inv = 1.0f / l_st[r];
      int gs = s0 + qr + quad * 4 + r;
      #pragma unroll
      for (int di = 0; di < 8; di++)
        O[(size_t)gs * DM + h * DH + di * 16 + l15] = accO[di][r] * inv;
    }
  }
}

// Merge NSPLIT partials + global absmax of result (feeds attn-out quant).
__global__ void flash_combine_k(const float* __restrict__ Op, const float* __restrict__ Mp,
                                const float* __restrict__ Lp, float* __restrict__ O,
                                unsigned* __restrict__ slot8) {
  const float fscale = 0.08838834764831845f * 1.4426950408889634f;
  const int t = threadIdx.x, lane = t & 63, w = t >> 6;   // 1024 thr, 16 waves
  const size_t SP = (size_t)NH * SEQ * DH, MR = (size_t)NH * SEQ;
  float lm = 0.f;
  for (int row = blockIdx.x * 16 + w; row < NH * SEQ; row += gridDim.x * 16) {
    float m0 = Mp[row], m1 = Mp[MR + row], m2 = Mp[2 * MR + row], m3 = Mp[3 * MR + row];
    float M = fmaxf(fmaxf(m0, m1), fmaxf(m2, m3));
    float w0 = exp2f((m0 - M) * fscale), w1 = exp2f((m1 - M) * fscale);
    float w2 = exp2f((m2 - M) * fscale), w3 = exp2f((m3 - M) * fscale);
    float inv = 1.0f / (Lp[row] * w0 + Lp[MR + row] * w1 + Lp[2 * MR + row] * w2 + Lp[3 * MR + row] * w3);
    int h = row / SEQ, s = row % SEQ;
    size_t ob = (size_t)s * DM + h * DH, ib = (size_t)row * DH;
    #pragma unroll
    for (int j = 0; j < 2; j++) {
      int d = lane + j * 64;
      float v = (Op[ib + d] * w0 + Op[SP + ib + d] * w1 +
                 Op[2 * SP + ib + d] * w2 + Op[3 * SP + ib + d] * w3) * inv;
      O[ob + d] = v;
      lm = fmaxf(lm, fabsf(v));
    }
  }
  lm = block_allmax_n(lm);
  if (t == 0) atomicMax(slot8, __float_as_uint(lm));
}

extern "C" void kernel_launch(void* const* d_in, const int* in_sizes, int n_in,
                              void* d_out, int out_size, void* d_ws, size_t ws_size,
                              hipStream_t stream) {
  (void)in_sizes; (void)n_in; (void)out_size;
  const void* hs   = d_in[0];
  const void* es   = d_in[1];
  const void* cosb = d_in[2];
  const void* sinb = d_in[3];
  const void* W[8]; const void* Bv[8];
  for (int i = 0; i < 8; i++) { W[i] = d_in[4 + 2 * i]; Bv[i] = d_in[5 + 2 * i]; }
  const void* nq  = d_in[20];
  const void* nk  = d_in[21];
  const void* naq = d_in[22];
  const void* nak = d_in[23];

  char* ws = (char*)d_ws;
  size_t off = 0;
  auto take = [&](size_t b) { char* p = ws + off; off += (b + 255) & ~(size_t)255; return p; };
  const size_t T = (size_t)NH * SEQ * DH * 4;      // 18.87 MB (one fp32 qkv tensor)

  unsigned* slots = (unsigned*)take(16 * SSTR * 4);   // 9 scale slots + flag, 128 B apart
  int* flagp = (int*)(slots + 15 * SSTR);
  float* wsc = (float*)take(8ull * DM * 4);

  size_t here = off;
  size_t need_base  = 4 * T + T + 3 * (T / 2) + 2 * ((size_t)NSPLIT * NH * SEQ * 4 + 256) + 1024;
  bool do_split = here + need_base <= ws_size;
  size_t region_sz = do_split ? 4 * T : 3 * T;

  char* region = take(region_sz);                  // qf,kf,vf; later Opart(+attnq)
  float* qf = (float*)region;
  float* kf = (float*)(region + T);
  float* vf = (float*)(region + 2 * T);
  float* Opart = (float*)region;
  __bf16* attnq = (__bf16*)region;                 // after combine (Opart dead)
  char* attnfR = take(T);                          // hq+eq early; attnf after flash
  __bf16* hq = (__bf16*)attnfR;
  __bf16* eq = (__bf16*)(attnfR + (size_t)L_IMG * DM * 2);
  float* attnf = (float*)attnfR;
  __bf16* qb  = (__bf16*)take(T / 2);
  __bf16* kb  = (__bf16*)take(T / 2);
  __bf16* vtb = (__bf16*)take(T / 2);
  float* Mpart = (float*)take((size_t)NSPLIT * NH * SEQ * 4);
  float* Lpart = (float*)take((size_t)NSPLIT * NH * SEQ * 4);
  bool do_prequant = (off + 8ull * DM * DM * 2 + 256 <= ws_size);
  __bf16* wq = do_prequant ? (__bf16*)take(8ull * DM * DM * 2) : nullptr;

  hipMemsetAsync(slots, 0, 16 * SSTR * 4, stream);
  detect_k<<<1, 64, 0, stream>>>(cosb, flagp);

  Ptrs8 win;
  for (int i = 0; i < 8; i++) win.p[i] = W[i];
  if (do_prequant)
    quant_weights_k<<<dim3(DM, 8), 256, 0, stream>>>(win, wq, wsc, flagp);
  else
    weight_scales_k<<<dim3(DM, 8), 256, 0, stream>>>(win, wsc, flagp);

  absmax_he_k<<<512, 256, 0, stream>>>(hs, es, slots, slots + SSTR, flagp);
  quant_he_k<<<1024, 256, 0, stream>>>(hs, es, slots, hq, eq, flagp);

  GemmArgs ga;
  ga.hq = hq; ga.eq = eq; ga.attnq = attnq; ga.wqp = wq;
  for (int i = 0; i < 8; i++) { ga.Wraw[i] = W[i]; ga.bias[i] = Bv[i]; }
  ga.wsc = wsc; ga.outs[0] = qf; ga.outs[1] = kf; ga.outs[2] = vf;
  ga.dout = d_out; ga.slots = slots; ga.flagp = flagp;

  if (do_prequant)
    gemm_f<0, 1><<<dim3(16, 18, 3), 256, 0, stream>>>(ga);
  else
    gemm_f<0, 0><<<dim3(16, 18, 3), 256, 0, stream>>>(ga);

  rms_absmax_v_k<<<256, 1024, 0, stream>>>(qf, kf, vf, nq, naq, nk, nak, slots, flagp);
  rope2_k<<<1024, 256, 0, stream>>>(qf, kf, cosb, sinb, slots, qb, kb, flagp);
  quant_transpose_v_k<<<dim3(SEQ / 64, DH / 64, NH), 256, 0, stream>>>(vf, slots, vtb);

  if (do_split) {
    flash_attn_k<1><<<dim3(SEQ / 64, NH, NSPLIT), 256, 0, stream>>>(qb, kb, vtb, nullptr,
                                                                    Opart, Mpart, Lpart);
    flash_combine_k<<<288, 1024, 0, stream>>>(Opart, Mpart, Lpart, attnf, slots + 8 * SSTR);
  } else {
    flash_attn_k<0><<<dim3(SEQ / 64, NH), 256, 0, stream>>>(qb, kb, vtb, attnf,
                                                            nullptr, nullptr, nullptr);
    absmax_f32_k<<<256, 256, 0, stream>>>(attnf, SEQ * DM, slots + 8 * SSTR);
  }
  quant_f32x8_k<<<1024, 256, 0, stream>>>(attnf, SEQ * DM / 8, slots + 8 * SSTR, attnq);

  if (do_prequant)
    gemm_f<1, 1><<<dim3(16, 18), 256, 0, stream>>>(ga);
  else
    gemm_f<1, 0><<<dim3(16, 18), 256, 0, stream>>>(ga);
}